// Round 2
// 2015.209 us; speedup vs baseline: 1.3762x; 1.3762x over previous
//
#include <hip/hip_runtime.h>

// ---- constants ----
#define BB 4
#define TT 1024
#define CC 1024
#define NH 16
#define NKV 4
#define HD 64
#define FFNH 4096
#define CAD 32
#define TQ 64
#define TK 64

typedef short bf16x8 __attribute__((ext_vector_type(8)));
typedef float f32x4  __attribute__((ext_vector_type(4)));

#define AS1 __attribute__((address_space(1)))
#define AS3 __attribute__((address_space(3)))

__device__ __forceinline__ float sigf(float x){ return 1.f/(1.f+__expf(-x)); }
__device__ __forceinline__ float geluf(float x){ return 0.5f*x*(1.f+erff(x*0.70710678118654752f)); }

// fp32 -> bf16 (round-to-nearest-even), and back
__device__ __forceinline__ unsigned short f2bf(float f){
  unsigned int u = __float_as_uint(f);
  u += 0x7fffu + ((u >> 16) & 1u);
  return (unsigned short)(u >> 16);
}
__device__ __forceinline__ float bf2f(unsigned short h){
  return __uint_as_float(((unsigned int)h) << 16);
}

// ---- rmsnorm over last dim (1024), emitting bf16 hi/lo pair ----
__global__ __launch_bounds__(256) void rmsnorm_pair_k(const float* __restrict__ x,
    unsigned short* __restrict__ oh, unsigned short* __restrict__ ol){
  int row = blockIdx.x;
  const float* xr = x + (size_t)row * CC;
  float v[4]; float ss = 0.f;
  #pragma unroll
  for (int i = 0; i < 4; i++){ v[i] = xr[threadIdx.x + 256*i]; ss += v[i]*v[i]; }
  #pragma unroll
  for (int off = 1; off < 64; off <<= 1) ss += __shfl_xor(ss, off);
  __shared__ float red[4];
  if ((threadIdx.x & 63) == 0) red[threadIdx.x >> 6] = ss;
  __syncthreads();
  float tot = red[0]+red[1]+red[2]+red[3];
  float rs = rsqrtf(tot * (1.f/CC) + 1e-6f);
  size_t base = (size_t)row * CC;
  #pragma unroll
  for (int i = 0; i < 4; i++){
    float r = v[i]*rs;
    unsigned short h = f2bf(r);
    oh[base + threadIdx.x + 256*i] = h;
    ol[base + threadIdx.x + 256*i] = f2bf(r - bf2f(h));
  }
}

// ---- generic fp32 -> bf16 hi/lo splitter (for weights) ----
__global__ __launch_bounds__(256) void split_k(const float* __restrict__ in,
    unsigned short* __restrict__ hi, unsigned short* __restrict__ lo, int n4){
  int i = blockIdx.x*256 + threadIdx.x;
  if (i >= n4) return;
  float4 v = ((const float4*)in)[i];
  unsigned short h0 = f2bf(v.x), h1 = f2bf(v.y), h2v = f2bf(v.z), h3 = f2bf(v.w);
  ushort4 hv = { h0, h1, h2v, h3 };
  ushort4 lv = { f2bf(v.x - bf2f(h0)), f2bf(v.y - bf2f(h1)),
                 f2bf(v.z - bf2f(h2v)), f2bf(v.w - bf2f(h3)) };
  ((ushort4*)hi)[i] = hv;
  ((ushort4*)lo)[i] = lv;
}

// ---- bf16x3 MFMA GEMM: C[M,N] = A[M,K] * W[N,K]^T, fp32 accuracy via hi/lo split.
//      128x128 tile, BK=32, 4 waves (2x2), mfma_f32_16x16x32_bf16.
//      global_load_lds(16B) staging with pre-swizzled GLOBAL source (chunk ^= (row>>1)&3),
//      linear LDS dest; ds_read_b128 fragment reads use the same XOR -> 2-way (free).
//      EPI: 0=plain store, 1=relu^2 ----
template<int EPI>
__global__ __launch_bounds__(256) void gemm3_k(
    const unsigned short* __restrict__ Ah, const unsigned short* __restrict__ Al,
    const unsigned short* __restrict__ Wh, const unsigned short* __restrict__ Wl,
    float* __restrict__ C, int M, int N, int K)
{
  __shared__ unsigned short AhS[128*32];
  __shared__ unsigned short AlS[128*32];
  __shared__ unsigned short WhS[128*32];
  __shared__ unsigned short WlS[128*32];
  int tid  = threadIdx.x;
  int lane = tid & 63, wave = tid >> 6;
  int wr = wave >> 1, wc = wave & 1;
  int m0 = blockIdx.y << 7, n0 = blockIdx.x << 7;
  int lr = lane & 15, lc = lane >> 4;

  // fragment LDS byte offsets (fixed across K-steps)
  int offA[4], offB[4];
  #pragma unroll
  for (int m = 0; m < 4; m++){
    int row = wr*64 + m*16 + lr;
    offA[m] = row*64 + ((lc ^ ((row >> 1) & 3)) << 4);
  }
  #pragma unroll
  for (int n = 0; n < 4; n++){
    int row = wc*64 + n*16 + lr;
    offB[n] = row*64 + ((lc ^ ((row >> 1) & 3)) << 4);
  }

  f32x4 acc[4][4] = {};

  for (int k0 = 0; k0 < K; k0 += 32){
    __syncthreads();   // previous compute done; LDS safe to overwrite

    // stage 4 tiles: per wave 2 x global_load_lds(16B) per tile
    {
      const unsigned short* srcs[4] = { Ah, Al, Wh, Wl };
      unsigned short* dsts[4] = { AhS, AlS, WhS, WlS };
      int rb[4] = { m0, m0, n0, n0 };
      #pragma unroll
      for (int tle = 0; tle < 4; tle++){
        #pragma unroll
        for (int i = 0; i < 2; i++){
          int s = i*256 + tid;
          int row = s >> 2;
          int c = (s & 3) ^ ((row >> 1) & 3);          // pre-swizzle global source
          const unsigned short* gp = srcs[tle] + (size_t)(rb[tle] + row)*K + (k0 + c*8);
          unsigned short* lp = dsts[tle] + i*2048 + wave*512;   // wave-uniform base
          __builtin_amdgcn_global_load_lds((const AS1 void*)gp, (AS3 void*)lp, 16, 0, 0);
        }
      }
    }
    __syncthreads();   // staging complete (barrier drains vmcnt)

    bf16x8 ah[4], al[4], bh[4], bl[4];
    #pragma unroll
    for (int m = 0; m < 4; m++){
      ah[m] = *(const bf16x8*)((const char*)AhS + offA[m]);
      al[m] = *(const bf16x8*)((const char*)AlS + offA[m]);
    }
    #pragma unroll
    for (int n = 0; n < 4; n++){
      bh[n] = *(const bf16x8*)((const char*)WhS + offB[n]);
      bl[n] = *(const bf16x8*)((const char*)WlS + offB[n]);
    }
    #pragma unroll
    for (int m = 0; m < 4; m++){
      #pragma unroll
      for (int n = 0; n < 4; n++){
        acc[m][n] = __builtin_amdgcn_mfma_f32_16x16x32_bf16(al[m], bh[n], acc[m][n], 0, 0, 0);
        acc[m][n] = __builtin_amdgcn_mfma_f32_16x16x32_bf16(ah[m], bl[n], acc[m][n], 0, 0, 0);
        acc[m][n] = __builtin_amdgcn_mfma_f32_16x16x32_bf16(ah[m], bh[n], acc[m][n], 0, 0, 0);
      }
    }
  }

  // C/D layout: col = lane&15, row = (lane>>4)*4 + reg  (guide m89/m91)
  #pragma unroll
  for (int m = 0; m < 4; m++){
    int r0 = m0 + wr*64 + m*16 + lc*4;
    #pragma unroll
    for (int n = 0; n < 4; n++){
      int col = n0 + wc*64 + n*16 + lr;
      #pragma unroll
      for (int r = 0; r < 4; r++){
        float z = acc[m][n][r];
        if (EPI == 1){ z = fmaxf(z, 0.f); z = z*z; }
        C[(size_t)(r0 + r)*N + col] = z;
      }
    }
  }
}

// ---- rope + head-rmsnorm * 1.2 (one wave per (b,t,head)) ----
__global__ __launch_bounds__(64) void rope_rms_k(float* __restrict__ q,
    const float* __restrict__ cs, const float* __restrict__ sn, int nh){
  int idx = blockIdx.x;                 // (b*T + t)*nh + h
  int t = (idx / nh) & (TT-1);
  float* qp = q + (size_t)idx * HD;
  int d = threadIdx.x;
  int dl = d & 31;
  float c = cs[t*32 + dl], s = sn[t*32 + dl];
  float v0 = qp[d];
  float vp = qp[(d < 32) ? d + 32 : d - 32];
  float r = (d < 32) ? (v0*c + vp*s) : (v0*c - vp*s);
  float ss = r*r;
  #pragma unroll
  for (int off = 1; off < 64; off <<= 1) ss += __shfl_xor(ss, off);
  float rs = rsqrtf(ss*(1.f/HD) + 1e-6f) * 1.2f;
  qp[d] = r*rs;
}

// ---- v += 3*sigmoid(xn[:,:12] @ wg^T) * ve  (xn from bf16 pair) ----
__global__ __launch_bounds__(256) void gatev_k(float* __restrict__ v,
    const unsigned short* __restrict__ xnh, const unsigned short* __restrict__ xnl,
    const float* __restrict__ ve, const float* __restrict__ wg){
  int bt = blockIdx.x;
  int tid = threadIdx.x;
  int kv = tid >> 6;
  float s = 0.f;
  #pragma unroll
  for (int j = 0; j < 12; j++){
    float xv = bf2f(xnh[(size_t)bt*CC + j]) + bf2f(xnl[(size_t)bt*CC + j]);
    s += xv*wg[kv*12+j];
  }
  float gate = 3.f * sigf(s);
  size_t i = (size_t)bt*(NKV*HD) + tid;
  v[i] += gate * ve[i];
}

// ---- flash attention: block = (b,h,64-row q-tile); fused refine conv.
//      Epilogue writes y as bf16 hi/lo pair for the o-projection GEMM. ----
__global__ __launch_bounds__(256) void fattn_k(
    const float* __restrict__ q, const float* __restrict__ k, const float* __restrict__ v,
    const float* __restrict__ pa, const float* __restrict__ rw,
    const float* __restrict__ alphap,
    unsigned short* __restrict__ yh, unsigned short* __restrict__ yl)
{
  int qt = blockIdx.x;         // 0..15
  int h  = blockIdx.y;
  int b  = blockIdx.z;
  int kv = h >> 2;
  int t0 = qt * TQ;
  int tid = threadIdx.x;
  int tx = tid & 15, ty = tid >> 4;

  __shared__ float Qs[HD][TQ+4];    // [d][row]  transposed
  __shared__ float Ks[HD][TK+4];    // [d][col]  transposed
  __shared__ float Vs[TK][HD+4];    // [kk][col]
  __shared__ float SB[66*68];       // pa tile [66][68]; later P^T [TK][TQ+4]

  for (int e = tid; e < TQ*HD/4; e += 256){
    int r = e >> 4;
    int d4 = (e & 15) << 2;
    const float* qp = q + (((size_t)(b*TT + t0 + r))*NH + h)*HD + d4;
    float4 val = *(const float4*)qp;
    Qs[d4+0][r] = val.x; Qs[d4+1][r] = val.y; Qs[d4+2][r] = val.z; Qs[d4+3][r] = val.w;
  }

  float alpha = *alphap;
  float w9[9];
  #pragma unroll
  for (int j = 0; j < 9; j++) w9[j] = rw[h*9+j]*alpha;

  float m_i[4], l_i[4], O[4][4];
  #pragma unroll
  for (int i=0;i<4;i++){ m_i[i] = -1e30f; l_i[i]=0.f;
    #pragma unroll
    for (int j=0;j<4;j++) O[i][j]=0.f; }

  for (int kt = 0; kt <= qt; kt++){
    int k0 = kt*TK;
    __syncthreads();
    for (int e = tid; e < TK*HD/4; e += 256){
      int r = e >> 4;
      int d4 = (e & 15) << 2;
      const float* kp = k + (((size_t)(b*TT + k0 + r))*NKV + kv)*HD + d4;
      float4 val = *(const float4*)kp;
      Ks[d4+0][r]=val.x; Ks[d4+1][r]=val.y; Ks[d4+2][r]=val.z; Ks[d4+3][r]=val.w;
      const float* vp = v + (((size_t)(b*TT + k0 + r))*NKV + kv)*HD + d4;
      *(float4*)&Vs[r][d4] = *(const float4*)vp;
    }
    for (int e = tid; e < 66*66; e += 256){
      int li = e / 66, lj = e - li*66;
      int gr = t0 - 1 + li, gc = k0 - 1 + lj;
      float pv = 0.f;
      if (gr >= 0 && gr < TT && gc >= 0 && gc < TT)
        pv = pa[((size_t)(b*NH + h)*TT + gr)*TT + gc];
      SB[li*68 + lj] = pv;
    }
    __syncthreads();
    float s[4][4];
    #pragma unroll
    for (int i=0;i<4;i++)
      #pragma unroll
      for (int j=0;j<4;j++) s[i][j]=0.f;
    #pragma unroll 8
    for (int d = 0; d < HD; d++){
      float4 a4 = *(const float4*)&Qs[d][ty*4];
      float4 b4 = *(const float4*)&Ks[d][tx*4];
      float av[4] = {a4.x,a4.y,a4.z,a4.w};
      float bv[4] = {b4.x,b4.y,b4.z,b4.w};
      #pragma unroll
      for (int i=0;i<4;i++)
        #pragma unroll
        for (int j=0;j<4;j++) s[i][j] += av[i]*bv[j];
    }
    #pragma unroll
    for (int i=0;i<4;i++){
      int lr = ty*4 + i;
      #pragma unroll
      for (int j=0;j<4;j++){
        int lcx = tx*4 + j;
        float cv = 0.f;
        #pragma unroll
        for (int dy=0; dy<3; dy++)
          #pragma unroll
          for (int dx=0; dx<3; dx++)
            cv += SB[(lr+dy)*68 + (lcx+dx)] * w9[dy*3+dx];
        float sv = s[i][j]*0.125f + cv;
        if (k0 + lcx > t0 + lr) sv = -1e30f;
        s[i][j] = sv;
      }
    }
    float p[4][4];
    #pragma unroll
    for (int i=0;i<4;i++){
      float rm = fmaxf(fmaxf(s[i][0],s[i][1]),fmaxf(s[i][2],s[i][3]));
      #pragma unroll
      for (int off=1; off<16; off<<=1) rm = fmaxf(rm, __shfl_xor(rm, off));
      float mn = fmaxf(m_i[i], rm);
      float sc = __expf(m_i[i] - mn);
      m_i[i] = mn;
      float rs = 0.f;
      #pragma unroll
      for (int j=0;j<4;j++){ float pv = __expf(s[i][j]-mn); p[i][j]=pv; rs += pv; }
      #pragma unroll
      for (int off=1; off<16; off<<=1) rs += __shfl_xor(rs, off);
      l_i[i] = l_i[i]*sc + rs;
      #pragma unroll
      for (int j=0;j<4;j++) O[i][j] *= sc;
    }
    __syncthreads();
    #pragma unroll
    for (int j=0;j<4;j++)
      #pragma unroll
      for (int i=0;i<4;i++)
        SB[(tx*4+j)*68 + ty*4 + i] = p[i][j];
    __syncthreads();
    #pragma unroll 8
    for (int kk=0; kk<TK; kk++){
      float4 a4 = *(const float4*)&SB[kk*68 + ty*4];
      float4 b4 = *(const float4*)&Vs[kk][tx*4];
      float av[4]={a4.x,a4.y,a4.z,a4.w};
      float bv[4]={b4.x,b4.y,b4.z,b4.w};
      #pragma unroll
      for (int i=0;i<4;i++)
        #pragma unroll
        for (int j=0;j<4;j++) O[i][j] += av[i]*bv[j];
    }
  }
  #pragma unroll
  for (int i=0;i<4;i++){
    float inv = 1.f / l_i[i];
    int t = t0 + ty*4 + i;
    size_t base = (((size_t)(b*TT + t))*NH + h)*HD + tx*4;
    #pragma unroll
    for (int j=0;j<4;j++){
      float val = O[i][j]*inv;
      unsigned short hv = f2bf(val);
      yh[base+j] = hv;
      yl[base+j] = f2bf(val - bf2f(hv));
    }
  }
}

// ---- CA: in-projection (K=1024 -> 32) ----
__global__ __launch_bounds__(256) void cain_k(const float* __restrict__ x,
    const float* __restrict__ pi, float* __restrict__ out){
  int bt = blockIdx.x;
  __shared__ float xs[CC];
  __shared__ float pr[8][33];
  for (int i = threadIdx.x; i < CC; i += 256) xs[i] = x[(size_t)bt*CC + i];
  __syncthreads();
  int d = threadIdx.x & 31, sl = threadIdx.x >> 5;
  const float* pip = pi + (size_t)d*CC + sl*128;
  float s = 0.f;
  #pragma unroll 8
  for (int i = 0; i < 128; i++) s += xs[sl*128+i]*pip[i];
  pr[sl][d] = s;
  __syncthreads();
  if (threadIdx.x < 32){
    float tot = 0.f;
    #pragma unroll
    for (int j = 0; j < 8; j++) tot += pr[j][threadIdx.x];
    out[(size_t)bt*CAD + threadIdx.x] = tot;
  }
}

// ---- CA: depthwise conv over T + exact gelu ----
__global__ __launch_bounds__(256) void caconv_k(const float* __restrict__ hin,
    const float* __restrict__ cw, float* __restrict__ gout){
  int i = blockIdx.x*256 + threadIdx.x;   // < B*T*32
  int d = i & 31;
  int bt = i >> 5;
  int t = bt & (TT-1);
  float cc = hin[i];
  float hm = (t > 0)      ? hin[i-32] : 0.f;
  float hp = (t < TT-1)   ? hin[i+32] : 0.f;
  float hc = cc + 0.1f*(hm*cw[d*3] + cc*cw[d*3+1] + hp*cw[d*3+2]);
  gout[i] = geluf(hc);
}

// ---- CA: out-projection (K=32 -> 1024) ----
__global__ __launch_bounds__(256) void caout_k(const float* __restrict__ g,
    const float* __restrict__ po, float* __restrict__ out){
  int bt = blockIdx.x;
  __shared__ float gs[CAD];
  if (threadIdx.x < CAD) gs[threadIdx.x] = g[(size_t)bt*CAD + threadIdx.x];
  __syncthreads();
  for (int c = threadIdx.x; c < CC; c += 256){
    const float* pp = po + (size_t)c*CAD;
    float s = 0.f;
    #pragma unroll
    for (int d2 = 0; d2 < CAD; d2++) s += gs[d2]*pp[d2];
    out[(size_t)bt*CC + c] = s;
  }
}

// ---- x1 = x + attn_out * (1 + 0.1*tanh(ca1)) ----
__global__ __launch_bounds__(256) void x1_k(const float* __restrict__ x,
    const float* __restrict__ ao, const float* __restrict__ ca1, float* __restrict__ x1){
  size_t i = (size_t)blockIdx.x*256 + threadIdx.x;
  x1[i] = x[i] + ao[i] * (1.f + 0.1f*tanhf(ca1[i]));
}

// ---- FFN depthwise conv over T ----
__global__ __launch_bounds__(256) void ffnconv_k(const float* __restrict__ hin,
    const float* __restrict__ cw, float* __restrict__ hout){
  size_t i = (size_t)blockIdx.x*256 + threadIdx.x;   // < B*T*4096
  int c = (int)(i & (FFNH-1));
  size_t bt = i >> 12;
  int t = (int)(bt & (TT-1));
  float cc = hin[i];
  float hm = (t > 0)    ? hin[i - FFNH] : 0.f;
  float hp = (t < TT-1) ? hin[i + FFNH] : 0.f;
  hout[i] = cc + 0.1f*(hm*cw[c*3] + cc*cw[c*3+1] + hp*cw[c*3+2]);
}

// ---- FFN conv, last pass: emit bf16 hi/lo pair for the ffn_out GEMM ----
__global__ __launch_bounds__(256) void ffnconv_pair_k(const float* __restrict__ hin,
    const float* __restrict__ cw, unsigned short* __restrict__ hh, unsigned short* __restrict__ hl){
  size_t i = (size_t)blockIdx.x*256 + threadIdx.x;
  int c = (int)(i & (FFNH-1));
  size_t bt = i >> 12;
  int t = (int)(bt & (TT-1));
  float cc = hin[i];
  float hm = (t > 0)    ? hin[i - FFNH] : 0.f;
  float hp = (t < TT-1) ? hin[i + FFNH] : 0.f;
  float r = cc + 0.1f*(hm*cw[c*3] + cc*cw[c*3+1] + hp*cw[c*3+2]);
  unsigned short hv = f2bf(r);
  hh[i] = hv;
  hl[i] = f2bf(r - bf2f(hv));
}

// ---- vit scalar gate ----
__global__ __launch_bounds__(256) void vit_k(const float* __restrict__ x1,
    const float* __restrict__ w1, const float* __restrict__ w2,
    float* __restrict__ vout){
  int bt = blockIdx.x;
  __shared__ float xs[CC];
  __shared__ float pr[8][33];
  __shared__ float g32[32];
  for (int i = threadIdx.x; i < CC; i += 256) xs[i] = x1[(size_t)bt*CC + i];
  __syncthreads();
  int d = threadIdx.x & 31, sl = threadIdx.x >> 5;
  const float* wp = w1 + (size_t)d*CC + sl*128;
  float s = 0.f;
  #pragma unroll 8
  for (int i = 0; i < 128; i++) s += xs[sl*128+i]*wp[i];
  pr[sl][d] = s;
  __syncthreads();
  if (threadIdx.x < 32){
    float tot = 0.f;
    #pragma unroll
    for (int j = 0; j < 8; j++) tot += pr[j][threadIdx.x];
    g32[threadIdx.x] = geluf(tot);
  }
  __syncthreads();
  if (threadIdx.x == 0){
    float s2 = 0.f;
    #pragma unroll
    for (int d2 = 0; d2 < 32; d2++) s2 += g32[d2]*w2[d2];
    vout[bt] = sigf(s2);
  }
}

// ---- vit smoothing + threshold ----
__global__ __launch_bounds__(256) void vitsm_k(const float* __restrict__ vin, float* __restrict__ vout){
  int i = blockIdx.x*256 + threadIdx.x;  // < B*T
  int t = i & (TT-1), b = i >> 10;
  float s = 0.f;
  #pragma unroll
  for (int dd = -2; dd <= 2; dd++){
    int tt = t + dd;
    if (tt >= 0 && tt < TT) s += vin[(b << 10) + tt];
  }
  s *= 0.2f;
  float vv = 0.7f*vin[i] + 0.3f*s;
  vout[i] = (vv > 0.3f) ? vv : 0.1f*vv;
}

// ---- final: out = x1 + mlp*sig(g)*(1+0.1*tanh(ca2)) * vit ----
__global__ __launch_bounds__(256) void final_k(const float* __restrict__ x1,
    const float* __restrict__ mlpraw, const float* __restrict__ g,
    const float* __restrict__ ca2, const float* __restrict__ vsm,
    float* __restrict__ out){
  size_t i = (size_t)blockIdx.x*256 + threadIdx.x;
  size_t bt = i >> 10;
  float mlp = mlpraw[i] * sigf(g[i]) * (1.f + 0.1f*tanhf(ca2[i]));
  out[i] = x1[i] + mlp * vsm[bt];
}

extern "C" void kernel_launch(void* const* d_in, const int* in_sizes, int n_in,
                              void* d_out, int out_size, void* d_ws, size_t ws_size,
                              hipStream_t stream) {
  (void)in_sizes; (void)n_in; (void)out_size; (void)ws_size;
  const float* x     = (const float*)d_in[0];
  const float* ve    = (const float*)d_in[1];
  const float* cs    = (const float*)d_in[2];
  const float* sn    = (const float*)d_in[3];
  const float* pa    = (const float*)d_in[4];
  const float* w_q   = (const float*)d_in[5];
  const float* w_k   = (const float*)d_in[6];
  const float* w_v   = (const float*)d_in[7];
  const float* w_o   = (const float*)d_in[8];
  const float* w_vg  = (const float*)d_in[9];
  const float* rfw   = (const float*)d_in[10];
  const float* ralp  = (const float*)d_in[11];
  const float* capi  = (const float*)d_in[12];
  const float* cacw  = (const float*)d_in[13];
  const float* capo  = (const float*)d_in[14];
  const float* ffin  = (const float*)d_in[15];
  const float* ffcw  = (const float*)d_in[16];
  const float* ffout = (const float*)d_in[17];
  const float* ffgt  = (const float*)d_in[18];
  const float* vw1   = (const float*)d_in[19];
  const float* vw2   = (const float*)d_in[20];

  // ---- workspace layout (byte offsets; lifetimes disjoint where aliased) ----
  // total footprint: 232 MiB
  const size_t M4  = (size_t)BB*TT*CC;      // 4,194,304 elements
  const size_t MB1 = 1ull << 20;
  char* WSB = (char*)d_ws;

  unsigned short* xnh = (unsigned short*)WSB;          //  0..16MiB: xn/xm bf16 pair
  unsigned short* xnl = xnh + M4;
  float* ca1 = (float*)WSB;                            //  (alias, after xn consumed)
  float* qb  = (float*)(WSB + 16*MB1);                 // 16..32: q fp32 (later ffn gate)
  float* kb  = (float*)(WSB + 32*MB1);                 // 32..36: k fp32
  unsigned short* ffgp = (unsigned short*)(WSB + 32*MB1); // (alias after fattn: ffgt pair)
  float* vb  = (float*)(WSB + 36*MB1);                 // 36..40: v fp32
  float* cah = (float*)(WSB + 36*MB1);                 // (alias after fattn)
  float* cag = cah + (size_t)BB*TT*CAD;
  float* vtb = cag + (size_t)BB*TT*CAD;
  float* vsm = vtb + (size_t)BB*TT;
  float* ao  = (float*)(WSB + 40*MB1);                 // 40..56: attn_out (later mlp raw)
  float* x1b = (float*)(WSB + 56*MB1);                 // 56..72: x1 fp32 (early: y pair)
  unsigned short* yh = (unsigned short*)x1b;
  unsigned short* yl = yh + M4;
  float* hb  = (float*)(WSB + 72*MB1);                 // 72..136: h fp32 (later h pair)
  unsigned short* hh = (unsigned short*)hb;
  unsigned short* hl = hh + 4*M4;
  float* h2  = (float*)(WSB + 136*MB1);                // 136..200: conv ping (early: qkvo pairs, late: ca2)
  unsigned short* wqp = (unsigned short*)(WSB + 136*MB1);
  unsigned short* wkp = (unsigned short*)(WSB + 140*MB1);
  unsigned short* wvp = (unsigned short*)(WSB + 141*MB1);
  unsigned short* wop = (unsigned short*)(WSB + 142*MB1);
  float* ca2 = h2;
  unsigned short* ffip = (unsigned short*)(WSB + 200*MB1); // 200..216: ffn_in pair (hi M4, lo M4 shorts)
  unsigned short* ffop = (unsigned short*)(WSB + 216*MB1); // 216..232: ffn_out pair

  const int BT = BB*TT;                     // 4096
  const int WQN = NH*HD*CC;                 // 1,048,576
  const int WKN = NKV*HD*CC;                // 262,144

  // weight splits into regions free at this point
  split_k<<<WQN/1024, 256, 0, stream>>>(w_q, wqp, wqp + WQN, WQN/4);
  split_k<<<WKN/1024, 256, 0, stream>>>(w_k, wkp, wkp + WKN, WKN/4);
  split_k<<<WKN/1024, 256, 0, stream>>>(w_v, wvp, wvp + WKN, WKN/4);
  split_k<<<WQN/1024, 256, 0, stream>>>(w_o, wop, wop + WQN, WQN/4);
  // ffn_in / ffn_out are each M4 floats -> n4 = M4/4, grid = M4/1024, lo at +M4 shorts
  split_k<<<M4/1024, 256, 0, stream>>>(ffin, ffip, ffip + M4, (int)(M4/4));
  split_k<<<M4/1024, 256, 0, stream>>>(ffout, ffop, ffop + M4, (int)(M4/4));

  rmsnorm_pair_k<<<BT, 256, 0, stream>>>(x, xnh, xnl);
  gemm3_k<0><<<dim3(8, 32), 256, 0, stream>>>(xnh, xnl, wqp, wqp + WQN, qb, BT, 1024, 1024);
  gemm3_k<0><<<dim3(2, 32), 256, 0, stream>>>(xnh, xnl, wkp, wkp + WKN, kb, BT, 256, 1024);
  gemm3_k<0><<<dim3(2, 32), 256, 0, stream>>>(xnh, xnl, wvp, wvp + WKN, vb, BT, 256, 1024);
  rope_rms_k<<<BT*NH, 64, 0, stream>>>(qb, cs, sn, NH);
  rope_rms_k<<<BT*NKV, 64, 0, stream>>>(kb, cs, sn, NKV);
  gatev_k<<<BT, 256, 0, stream>>>(vb, xnh, xnl, ve, w_vg);
  fattn_k<<<dim3(TT/TQ, NH, BB), 256, 0, stream>>>(qb, kb, vb, pa, rfw, ralp, yh, yl);
  gemm3_k<0><<<dim3(8, 32), 256, 0, stream>>>(yh, yl, wop, wop + WQN, ao, BT, 1024, 1024);
  // kb/vb regions now dead: ffgt pair + ca scratch live there
  split_k<<<WQN/1024, 256, 0, stream>>>(ffgt, ffgp, ffgp + WQN, WQN/4);
  cain_k<<<BT, 256, 0, stream>>>(x, capi, cah);
  caconv_k<<<BT*CAD/256, 256, 0, stream>>>(cah, cacw, cag);
  caout_k<<<BT, 256, 0, stream>>>(cag, capo, ca1);
  x1_k<<<BT*CC/256, 256, 0, stream>>>(x, ao, ca1, x1b);
  rmsnorm_pair_k<<<BT, 256, 0, stream>>>(x1b, xnh, xnl);      // xm pair
  gemm3_k<1><<<dim3(32, 32), 256, 0, stream>>>(xnh, xnl, ffip, ffip + M4, hb, BT, FFNH, 1024);
  ffnconv_k<<<BT*FFNH/256, 256, 0, stream>>>(hb, ffcw, h2);
  ffnconv_k<<<BT*FFNH/256, 256, 0, stream>>>(h2, ffcw, hb);
  ffnconv_k<<<BT*FFNH/256, 256, 0, stream>>>(hb, ffcw, h2);
  ffnconv_pair_k<<<BT*FFNH/256, 256, 0, stream>>>(h2, ffcw, hh, hl);
  gemm3_k<0><<<dim3(8, 32), 256, 0, stream>>>(xnh, xnl, ffgp, ffgp + WQN, qb, BT, 1024, 1024);
  gemm3_k<0><<<dim3(8, 32), 256, 0, stream>>>(hh, hl, ffop, ffop + M4, ao, BT, 1024, FFNH);
  cain_k<<<BT, 256, 0, stream>>>(x1b, capi, cah);
  caconv_k<<<BT*CAD/256, 256, 0, stream>>>(cah, cacw, cag);
  caout_k<<<BT, 256, 0, stream>>>(cag, capo, ca2);
  vit_k<<<BT, 256, 0, stream>>>(x1b, vw1, vw2, vtb);
  vitsm_k<<<BT/256, 256, 0, stream>>>(vtb, vsm);
  final_k<<<BT*CC/256, 256, 0, stream>>>(x1b, ao, qb, ca2, vsm, (float*)d_out);
}

// Round 4
// 1863.211 us; speedup vs baseline: 1.4885x; 1.0816x over previous
//
#include <hip/hip_runtime.h>

// ---- constants ----
#define BB 4
#define TT 1024
#define CC 1024
#define NH 16
#define NKV 4
#define HD 64
#define FFNH 4096
#define CAD 32
#define TQ 64
#define TK 64

typedef short bf16x8 __attribute__((ext_vector_type(8)));
typedef float f32x4  __attribute__((ext_vector_type(4)));

#define AS1 __attribute__((address_space(1)))
#define AS3 __attribute__((address_space(3)))

__device__ __forceinline__ float sigf(float x){ return 1.f/(1.f+__expf(-x)); }
__device__ __forceinline__ float geluf(float x){ return 0.5f*x*(1.f+erff(x*0.70710678118654752f)); }

// fp32 -> bf16 (round-to-nearest-even), and back
__device__ __forceinline__ unsigned short f2bf(float f){
  unsigned int u = __float_as_uint(f);
  u += 0x7fffu + ((u >> 16) & 1u);
  return (unsigned short)(u >> 16);
}
__device__ __forceinline__ float bf2f(unsigned short h){
  return __uint_as_float(((unsigned int)h) << 16);
}

// ---- rmsnorm over last dim (1024), emitting bf16 hi/lo pair ----
__global__ __launch_bounds__(256) void rmsnorm_pair_k(const float* __restrict__ x,
    unsigned short* __restrict__ oh, unsigned short* __restrict__ ol){
  int row = blockIdx.x;
  const float* xr = x + (size_t)row * CC;
  float v[4]; float ss = 0.f;
  #pragma unroll
  for (int i = 0; i < 4; i++){ v[i] = xr[threadIdx.x + 256*i]; ss += v[i]*v[i]; }
  #pragma unroll
  for (int off = 1; off < 64; off <<= 1) ss += __shfl_xor(ss, off);
  __shared__ float red[4];
  if ((threadIdx.x & 63) == 0) red[threadIdx.x >> 6] = ss;
  __syncthreads();
  float tot = red[0]+red[1]+red[2]+red[3];
  float rs = rsqrtf(tot * (1.f/CC) + 1e-6f);
  size_t base = (size_t)row * CC;
  #pragma unroll
  for (int i = 0; i < 4; i++){
    float r = v[i]*rs;
    unsigned short h = f2bf(r);
    oh[base + threadIdx.x + 256*i] = h;
    ol[base + threadIdx.x + 256*i] = f2bf(r - bf2f(h));
  }
}

// ---- generic fp32 -> bf16 hi/lo splitter (for weights) ----
__global__ __launch_bounds__(256) void split_k(const float* __restrict__ in,
    unsigned short* __restrict__ hi, unsigned short* __restrict__ lo, int n4){
  int i = blockIdx.x*256 + threadIdx.x;
  if (i >= n4) return;
  float4 v = ((const float4*)in)[i];
  unsigned short h0 = f2bf(v.x), h1 = f2bf(v.y), h2v = f2bf(v.z), h3 = f2bf(v.w);
  ushort4 hv = { h0, h1, h2v, h3 };
  ushort4 lv = { f2bf(v.x - bf2f(h0)), f2bf(v.y - bf2f(h1)),
                 f2bf(v.z - bf2f(h2v)), f2bf(v.w - bf2f(h3)) };
  ((ushort4*)hi)[i] = hv;
  ((ushort4*)lo)[i] = lv;
}

// ---- bf16x3 MFMA GEMM (verified round 2) ----
template<int EPI>
__global__ __launch_bounds__(256) void gemm3_k(
    const unsigned short* __restrict__ Ah, const unsigned short* __restrict__ Al,
    const unsigned short* __restrict__ Wh, const unsigned short* __restrict__ Wl,
    float* __restrict__ C, int M, int N, int K)
{
  __shared__ unsigned short AhS[128*32];
  __shared__ unsigned short AlS[128*32];
  __shared__ unsigned short WhS[128*32];
  __shared__ unsigned short WlS[128*32];
  int tid  = threadIdx.x;
  int lane = tid & 63, wave = tid >> 6;
  int wr = wave >> 1, wc = wave & 1;
  int m0 = blockIdx.y << 7, n0 = blockIdx.x << 7;
  int lr = lane & 15, lc = lane >> 4;

  int offA[4], offB[4];
  #pragma unroll
  for (int m = 0; m < 4; m++){
    int row = wr*64 + m*16 + lr;
    offA[m] = row*64 + ((lc ^ ((row >> 1) & 3)) << 4);
  }
  #pragma unroll
  for (int n = 0; n < 4; n++){
    int row = wc*64 + n*16 + lr;
    offB[n] = row*64 + ((lc ^ ((row >> 1) & 3)) << 4);
  }

  f32x4 acc[4][4] = {};

  for (int k0 = 0; k0 < K; k0 += 32){
    __syncthreads();
    {
      const unsigned short* srcs[4] = { Ah, Al, Wh, Wl };
      unsigned short* dsts[4] = { AhS, AlS, WhS, WlS };
      int rb[4] = { m0, m0, n0, n0 };
      #pragma unroll
      for (int tle = 0; tle < 4; tle++){
        #pragma unroll
        for (int i = 0; i < 2; i++){
          int s = i*256 + tid;
          int row = s >> 2;
          int c = (s & 3) ^ ((row >> 1) & 3);
          const unsigned short* gp = srcs[tle] + (size_t)(rb[tle] + row)*K + (k0 + c*8);
          unsigned short* lp = dsts[tle] + i*2048 + wave*512;
          __builtin_amdgcn_global_load_lds((const AS1 void*)gp, (AS3 void*)lp, 16, 0, 0);
        }
      }
    }
    __syncthreads();

    bf16x8 ah[4], al[4], bh[4], bl[4];
    #pragma unroll
    for (int m = 0; m < 4; m++){
      ah[m] = *(const bf16x8*)((const char*)AhS + offA[m]);
      al[m] = *(const bf16x8*)((const char*)AlS + offA[m]);
    }
    #pragma unroll
    for (int n = 0; n < 4; n++){
      bh[n] = *(const bf16x8*)((const char*)WhS + offB[n]);
      bl[n] = *(const bf16x8*)((const char*)WlS + offB[n]);
    }
    #pragma unroll
    for (int m = 0; m < 4; m++){
      #pragma unroll
      for (int n = 0; n < 4; n++){
        acc[m][n] = __builtin_amdgcn_mfma_f32_16x16x32_bf16(al[m], bh[n], acc[m][n], 0, 0, 0);
        acc[m][n] = __builtin_amdgcn_mfma_f32_16x16x32_bf16(ah[m], bl[n], acc[m][n], 0, 0, 0);
        acc[m][n] = __builtin_amdgcn_mfma_f32_16x16x32_bf16(ah[m], bh[n], acc[m][n], 0, 0, 0);
      }
    }
  }

  #pragma unroll
  for (int m = 0; m < 4; m++){
    int r0 = m0 + wr*64 + m*16 + lc*4;
    #pragma unroll
    for (int n = 0; n < 4; n++){
      int col = n0 + wc*64 + n*16 + lr;
      #pragma unroll
      for (int r = 0; r < 4; r++){
        float z = acc[m][n][r];
        if (EPI == 1){ z = fmaxf(z, 0.f); z = z*z; }
        C[(size_t)(r0 + r)*N + col] = z;
      }
    }
  }
}

// ---- rope + head-rmsnorm * 1.2 ----
__global__ __launch_bounds__(64) void rope_rms_k(float* __restrict__ q,
    const float* __restrict__ cs, const float* __restrict__ sn, int nh){
  int idx = blockIdx.x;
  int t = (idx / nh) & (TT-1);
  float* qp = q + (size_t)idx * HD;
  int d = threadIdx.x;
  int dl = d & 31;
  float c = cs[t*32 + dl], s = sn[t*32 + dl];
  float v0 = qp[d];
  float vp = qp[(d < 32) ? d + 32 : d - 32];
  float r = (d < 32) ? (v0*c + vp*s) : (v0*c - vp*s);
  float ss = r*r;
  #pragma unroll
  for (int off = 1; off < 64; off <<= 1) ss += __shfl_xor(ss, off);
  float rs = rsqrtf(ss*(1.f/HD) + 1e-6f) * 1.2f;
  qp[d] = r*rs;
}

// ---- v += 3*sigmoid(xn[:,:12] @ wg^T) * ve ----
__global__ __launch_bounds__(256) void gatev_k(float* __restrict__ v,
    const unsigned short* __restrict__ xnh, const unsigned short* __restrict__ xnl,
    const float* __restrict__ ve, const float* __restrict__ wg){
  int bt = blockIdx.x;
  int tid = threadIdx.x;
  int kv = tid >> 6;
  float s = 0.f;
  #pragma unroll
  for (int j = 0; j < 12; j++){
    float xv = bf2f(xnh[(size_t)bt*CC + j]) + bf2f(xnl[(size_t)bt*CC + j]);
    s += xv*wg[kv*12+j];
  }
  float gate = 3.f * sigf(s);
  size_t i = (size_t)bt*(NKV*HD) + tid;
  v[i] += gate * ve[i];
}

// ---- MFMA flash attention (S^T trick), bf16x3 for QK and PV; fused refine conv.
//      FIX r4: epilogue q index includes +16*w (wave strip offset).
//      FIX r4: Vs stride 65 -> 68 floats (16B-aligned float4 staging). ----
__global__ __launch_bounds__(256) void fattn_k(
    const float* __restrict__ q, const float* __restrict__ k, const float* __restrict__ v,
    const float* __restrict__ pa, const float* __restrict__ rw,
    const float* __restrict__ alphap,
    unsigned short* __restrict__ yh, unsigned short* __restrict__ yl)
{
  int qt = blockIdx.x;
  int h  = blockIdx.y;
  int b  = blockIdx.z;
  int kv = h >> 2;
  int t0 = qt * TQ;
  int tid = threadIdx.x;
  int lane = tid & 63, w = tid >> 6;
  int dl = lane & 15, gq = lane >> 4;

  __shared__ __align__(16) unsigned short Qh[4096], Ql[4096];   // [64 q][64 d] swz
  __shared__ __align__(16) unsigned short Kh[4096], Kl[4096];   // [64 k][64 d] swz
  __shared__ __align__(16) float Vs[64][68];                    // [k][d] fp32, 16B-aligned rows
  __shared__ __align__(16) unsigned short SBs[66*67];           // pa tile bf16
  __shared__ __align__(16) unsigned short Ph[4][1024], Pl[4][1024]; // per-wave P [16 q][64 k] swz

  // stage Q tile once
  #pragma unroll
  for (int it = 0; it < 4; it++){
    int s = it*256 + tid;
    int r = s >> 4, d4 = (s & 15) << 2;
    const float* qp = q + (((size_t)(b*TT + t0 + r))*NH + h)*HD + d4;
    float4 val = *(const float4*)qp;
    ushort4 hv = { f2bf(val.x), f2bf(val.y), f2bf(val.z), f2bf(val.w) };
    ushort4 lv = { f2bf(val.x - bf2f(hv.x)), f2bf(val.y - bf2f(hv.y)),
                   f2bf(val.z - bf2f(hv.z)), f2bf(val.w - bf2f(hv.w)) };
    int idx = r*64 + (((d4 >> 3) ^ (r & 7)) << 3) + (d4 & 7);
    *(ushort4*)&Qh[idx] = hv;
    *(ushort4*)&Ql[idx] = lv;
  }

  float alpha = *alphap;
  float w9[9];
  #pragma unroll
  for (int j = 0; j < 9; j++) w9[j] = rw[h*9+j]*alpha;

  __syncthreads();
  // Q B-fragments for this wave's q strip (q rows = 16w..16w+15)
  bf16x8 qfh[2], qfl[2];
  #pragma unroll
  for (int ks = 0; ks < 2; ks++){
    int row = 16*w + dl;
    int idx = row*64 + (((gq + 4*ks) ^ (row & 7)) << 3);
    qfh[ks] = *(const bf16x8*)&Qh[idx];
    qfl[ks] = *(const bf16x8*)&Ql[idx];
  }

  float m_i = -1e30f, l_i = 0.f;
  f32x4 acc_o[4] = {};
  int ql = 16*w + dl;      // lane's q (local in tile)

  for (int kt = 0; kt <= qt; kt++){
    int k0 = kt*TK;
    __syncthreads();   // prior tile's K/V/SB reads complete
    // stage K (bf16 pair, swizzled) + V (fp32)
    #pragma unroll
    for (int it = 0; it < 4; it++){
      int s = it*256 + tid;
      int r = s >> 4, d4 = (s & 15) << 2;
      const float* kp = k + (((size_t)(b*TT + k0 + r))*NKV + kv)*HD + d4;
      float4 val = *(const float4*)kp;
      ushort4 hv = { f2bf(val.x), f2bf(val.y), f2bf(val.z), f2bf(val.w) };
      ushort4 lv = { f2bf(val.x - bf2f(hv.x)), f2bf(val.y - bf2f(hv.y)),
                     f2bf(val.z - bf2f(hv.z)), f2bf(val.w - bf2f(hv.w)) };
      int idx = r*64 + (((d4 >> 3) ^ (r & 7)) << 3) + (d4 & 7);
      *(ushort4*)&Kh[idx] = hv;
      *(ushort4*)&Kl[idx] = lv;
      const float* vp = v + (((size_t)(b*TT + k0 + r))*NKV + kv)*HD + d4;
      *(float4*)&Vs[r][d4] = *(const float4*)vp;
    }
    // stage pa tile with halo (bf16)
    for (int e = tid; e < 66*66; e += 256){
      int li = e / 66, lj = e - li*66;
      int gr = t0 - 1 + li, gc = k0 - 1 + lj;
      float pv = 0.f;
      if (gr >= 0 && gr < TT && gc >= 0 && gc < TT)
        pv = pa[((size_t)(b*NH + h)*TT + gr)*TT + gc];
      SBs[li*67 + lj] = f2bf(pv);
    }
    __syncthreads();

    // S^T = K·Q^T  (rows = k, cols = q)
    f32x4 acc_s[4] = {};
    #pragma unroll
    for (int ks = 0; ks < 2; ks++){
      #pragma unroll
      for (int kf = 0; kf < 4; kf++){
        int row = 16*kf + dl;
        int idx = row*64 + (((gq + 4*ks) ^ (row & 7)) << 3);
        bf16x8 kh_ = *(const bf16x8*)&Kh[idx];
        bf16x8 kl_ = *(const bf16x8*)&Kl[idx];
        acc_s[kf] = __builtin_amdgcn_mfma_f32_16x16x32_bf16(kl_, qfh[ks], acc_s[kf], 0, 0, 0);
        acc_s[kf] = __builtin_amdgcn_mfma_f32_16x16x32_bf16(kh_, qfl[ks], acc_s[kf], 0, 0, 0);
        acc_s[kf] = __builtin_amdgcn_mfma_f32_16x16x32_bf16(kh_, qfh[ks], acc_s[kf], 0, 0, 0);
      }
    }

    // conv + scale + causal mask; lane elem (k = 16kf+4gq+reg, q = ql)
    #pragma unroll
    for (int kf = 0; kf < 4; kf++){
      int kb = 16*kf + 4*gq;
      float cv0=0.f, cv1=0.f, cv2=0.f, cv3=0.f;
      #pragma unroll
      for (int dy = 0; dy < 3; dy++){
        const unsigned short* rp = &SBs[(ql + dy)*67 + kb];
        float u0 = bf2f(rp[0]), u1 = bf2f(rp[1]), u2 = bf2f(rp[2]),
              u3 = bf2f(rp[3]), u4 = bf2f(rp[4]), u5 = bf2f(rp[5]);
        float wa = w9[dy*3+0], wb = w9[dy*3+1], wcq = w9[dy*3+2];
        cv0 += u0*wa + u1*wb + u2*wcq;
        cv1 += u1*wa + u2*wb + u3*wcq;
        cv2 += u2*wa + u3*wb + u4*wcq;
        cv3 += u3*wa + u4*wb + u5*wcq;
      }
      int grow = t0 + ql;
      float s0 = acc_s[kf][0]*0.125f + cv0; if (k0 + kb + 0 > grow) s0 = -1e30f;
      float s1 = acc_s[kf][1]*0.125f + cv1; if (k0 + kb + 1 > grow) s1 = -1e30f;
      float s2 = acc_s[kf][2]*0.125f + cv2; if (k0 + kb + 2 > grow) s2 = -1e30f;
      float s3 = acc_s[kf][3]*0.125f + cv3; if (k0 + kb + 3 > grow) s3 = -1e30f;
      acc_s[kf][0] = s0; acc_s[kf][1] = s1; acc_s[kf][2] = s2; acc_s[kf][3] = s3;
    }

    // online softmax over k (lane's q fixed): local 16 + cross-g shfl
    float rm = -1e30f;
    #pragma unroll
    for (int kf = 0; kf < 4; kf++){
      rm = fmaxf(rm, fmaxf(fmaxf(acc_s[kf][0], acc_s[kf][1]),
                           fmaxf(acc_s[kf][2], acc_s[kf][3])));
    }
    rm = fmaxf(rm, __shfl_xor(rm, 16));
    rm = fmaxf(rm, __shfl_xor(rm, 32));
    float mn = fmaxf(m_i, rm);
    float sc = __expf(m_i - mn);
    m_i = mn;
    float rs = 0.f;
    #pragma unroll
    for (int kf = 0; kf < 4; kf++){
      float p0 = __expf(acc_s[kf][0] - mn);
      float p1 = __expf(acc_s[kf][1] - mn);
      float p2 = __expf(acc_s[kf][2] - mn);
      float p3 = __expf(acc_s[kf][3] - mn);
      rs += p0 + p1 + p2 + p3;
      ushort4 hv = { f2bf(p0), f2bf(p1), f2bf(p2), f2bf(p3) };
      ushort4 lv = { f2bf(p0 - bf2f(hv.x)), f2bf(p1 - bf2f(hv.y)),
                     f2bf(p2 - bf2f(hv.z)), f2bf(p3 - bf2f(hv.w)) };
      int kbl = 16*kf + 4*gq;
      int idx = dl*64 + ((((kbl >> 3)) ^ (dl & 7)) << 3) + (kbl & 7);
      *(ushort4*)&Ph[w][idx] = hv;
      *(ushort4*)&Pl[w][idx] = lv;
    }
    rs += __shfl_xor(rs, 16);
    rs += __shfl_xor(rs, 32);
    l_i = l_i*sc + rs;

    // rescale O (O rows q = 4gq+reg -> fetch sc from lane 4gq+reg)
    float scR0 = __shfl(sc, gq*4 + 0);
    float scR1 = __shfl(sc, gq*4 + 1);
    float scR2 = __shfl(sc, gq*4 + 2);
    float scR3 = __shfl(sc, gq*4 + 3);
    #pragma unroll
    for (int nf = 0; nf < 4; nf++){
      acc_o[nf][0] *= scR0; acc_o[nf][1] *= scR1;
      acc_o[nf][2] *= scR2; acc_o[nf][3] *= scR3;
    }

    // O += P·V
    #pragma unroll
    for (int ks = 0; ks < 2; ks++){
      int idxp = dl*64 + (((gq + 4*ks) ^ (dl & 7)) << 3);
      bf16x8 pfh = *(const bf16x8*)&Ph[w][idxp];
      bf16x8 pfl = *(const bf16x8*)&Pl[w][idxp];
      #pragma unroll
      for (int nf = 0; nf < 4; nf++){
        bf16x8 vh_, vl_;
        #pragma unroll
        for (int i = 0; i < 8; i++){
          float vv = Vs[ks*32 + gq*8 + i][16*nf + dl];
          unsigned short hb_ = f2bf(vv);
          vh_[i] = (short)hb_;
          vl_[i] = (short)f2bf(vv - bf2f(hb_));
        }
        acc_o[nf] = __builtin_amdgcn_mfma_f32_16x16x32_bf16(pfl, vh_, acc_o[nf], 0, 0, 0);
        acc_o[nf] = __builtin_amdgcn_mfma_f32_16x16x32_bf16(pfh, vl_, acc_o[nf], 0, 0, 0);
        acc_o[nf] = __builtin_amdgcn_mfma_f32_16x16x32_bf16(pfh, vh_, acc_o[nf], 0, 0, 0);
      }
    }
  }

  // epilogue: O rows q = 16*w + 4*gq + reg, cols d = 16nf+dl
  float li0 = __shfl(l_i, gq*4 + 0);
  float li1 = __shfl(l_i, gq*4 + 1);
  float li2 = __shfl(l_i, gq*4 + 2);
  float li3 = __shfl(l_i, gq*4 + 3);
  float inv0 = 1.f/li0, inv1 = 1.f/li1, inv2 = 1.f/li2, inv3 = 1.f/li3;
  #pragma unroll
  for (int nf = 0; nf < 4; nf++){
    int dcol = 16*nf + dl;
    #pragma unroll
    for (int reg = 0; reg < 4; reg++){
      float invv = (reg == 0) ? inv0 : (reg == 1) ? inv1 : (reg == 2) ? inv2 : inv3;
      float val = acc_o[nf][reg] * invv;
      size_t bix = (((size_t)(b*TT + t0 + 16*w + gq*4 + reg))*NH + h)*HD + dcol;
      unsigned short hv = f2bf(val);
      yh[bix] = hv;
      yl[bix] = f2bf(val - bf2f(hv));
    }
  }
}

// ---- CA: in-projection (K=1024 -> 32) ----
__global__ __launch_bounds__(256) void cain_k(const float* __restrict__ x,
    const float* __restrict__ pi, float* __restrict__ out){
  int bt = blockIdx.x;
  __shared__ float xs[CC];
  __shared__ float pr[8][33];
  for (int i = threadIdx.x; i < CC; i += 256) xs[i] = x[(size_t)bt*CC + i];
  __syncthreads();
  int d = threadIdx.x & 31, sl = threadIdx.x >> 5;
  const float* pip = pi + (size_t)d*CC + sl*128;
  float s = 0.f;
  #pragma unroll 8
  for (int i = 0; i < 128; i++) s += xs[sl*128+i]*pip[i];
  pr[sl][d] = s;
  __syncthreads();
  if (threadIdx.x < 32){
    float tot = 0.f;
    #pragma unroll
    for (int j = 0; j < 8; j++) tot += pr[j][threadIdx.x];
    out[(size_t)bt*CAD + threadIdx.x] = tot;
  }
}

// ---- CA: depthwise conv over T + exact gelu ----
__global__ __launch_bounds__(256) void caconv_k(const float* __restrict__ hin,
    const float* __restrict__ cw, float* __restrict__ gout){
  int i = blockIdx.x*256 + threadIdx.x;
  int d = i & 31;
  int bt = i >> 5;
  int t = bt & (TT-1);
  float cc = hin[i];
  float hm = (t > 0)      ? hin[i-32] : 0.f;
  float hp = (t < TT-1)   ? hin[i+32] : 0.f;
  float hc = cc + 0.1f*(hm*cw[d*3] + cc*cw[d*3+1] + hp*cw[d*3+2]);
  gout[i] = geluf(hc);
}

// ---- CA: out-projection (K=32 -> 1024) ----
__global__ __launch_bounds__(256) void caout_k(const float* __restrict__ g,
    const float* __restrict__ po, float* __restrict__ out){
  int bt = blockIdx.x;
  __shared__ float gs[CAD];
  if (threadIdx.x < CAD) gs[threadIdx.x] = g[(size_t)bt*CAD + threadIdx.x];
  __syncthreads();
  for (int c = threadIdx.x; c < CC; c += 256){
    const float* pp = po + (size_t)c*CAD;
    float s = 0.f;
    #pragma unroll
    for (int d2 = 0; d2 < CAD; d2++) s += gs[d2]*pp[d2];
    out[(size_t)bt*CC + c] = s;
  }
}

// ---- x1 = x + attn_out * (1 + 0.1*tanh(ca1)) ----
__global__ __launch_bounds__(256) void x1_k(const float* __restrict__ x,
    const float* __restrict__ ao, const float* __restrict__ ca1, float* __restrict__ x1){
  size_t i = (size_t)blockIdx.x*256 + threadIdx.x;
  x1[i] = x[i] + ao[i] * (1.f + 0.1f*tanhf(ca1[i]));
}

// ---- fused 4-pass FFN depthwise conv (register cascade), bf16 pair out ----
__global__ __launch_bounds__(256) void ffnconv4_k(const float* __restrict__ hin,
    const float* __restrict__ cw, unsigned short* __restrict__ hh, unsigned short* __restrict__ hl){
  int c  = blockIdx.x*256 + threadIdx.x;     // channel
  int ta = blockIdx.y*64;                    // t-chunk start
  int b  = blockIdx.z;
  float w0 = cw[c*3+0], w1 = cw[c*3+1], w2 = cw[c*3+2];
  size_t base = (size_t)b*TT*FFNH + c;
  float i0=0.f,i1=0.f,i2=0.f;      // in(t-2..t)
  float a0=0.f,a1=0.f,a2=0.f;      // s1(t-3..t-1)
  float b0=0.f,b1=0.f,b2=0.f;      // s2(t-4..t-2)
  float c0=0.f,c1=0.f,c2=0.f;      // s3(t-5..t-3)
  for (int t = ta-4; t <= ta+67; t++){
    float iv = 0.f;
    if (t >= 0 && t < TT) iv = hin[base + (size_t)t*FFNH];
    i0 = i1; i1 = i2; i2 = iv;
    float s1 = i1 + 0.1f*(i0*w0 + i1*w1 + i2*w2);
    if (t-1 < 0 || t-1 >= TT) s1 = 0.f;
    a0 = a1; a1 = a2; a2 = s1;
    float s2 = a1 + 0.1f*(a0*w0 + a1*w1 + a2*w2);
    if (t-2 < 0 || t-2 >= TT) s2 = 0.f;
    b0 = b1; b1 = b2; b2 = s2;
    float s3 = b1 + 0.1f*(b0*w0 + b1*w1 + b2*w2);
    if (t-3 < 0 || t-3 >= TT) s3 = 0.f;
    c0 = c1; c1 = c2; c2 = s3;
    float s4 = c1 + 0.1f*(c0*w0 + c1*w1 + c2*w2);
    int t4 = t-4;
    if (t4 >= ta){
      size_t oix = base + (size_t)t4*FFNH;
      unsigned short hv = f2bf(s4);
      hh[oix] = hv;
      hl[oix] = f2bf(s4 - bf2f(hv));
    }
  }
}

// ---- vit scalar gate ----
__global__ __launch_bounds__(256) void vit_k(const float* __restrict__ x1,
    const float* __restrict__ w1, const float* __restrict__ w2,
    float* __restrict__ vout){
  int bt = blockIdx.x;
  __shared__ float xs[CC];
  __shared__ float pr[8][33];
  __shared__ float g32[32];
  for (int i = threadIdx.x; i < CC; i += 256) xs[i] = x1[(size_t)bt*CC + i];
  __syncthreads();
  int d = threadIdx.x & 31, sl = threadIdx.x >> 5;
  const float* wp = w1 + (size_t)d*CC + sl*128;
  float s = 0.f;
  #pragma unroll 8
  for (int i = 0; i < 128; i++) s += xs[sl*128+i]*wp[i];
  pr[sl][d] = s;
  __syncthreads();
  if (threadIdx.x < 32){
    float tot = 0.f;
    #pragma unroll
    for (int j = 0; j < 8; j++) tot += pr[j][threadIdx.x];
    g32[threadIdx.x] = geluf(tot);
  }
  __syncthreads();
  if (threadIdx.x == 0){
    float s2 = 0.f;
    #pragma unroll
    for (int d2 = 0; d2 < 32; d2++) s2 += g32[d2]*w2[d2];
    vout[bt] = sigf(s2);
  }
}

// ---- vit smoothing + threshold ----
__global__ __launch_bounds__(256) void vitsm_k(const float* __restrict__ vin, float* __restrict__ vout){
  int i = blockIdx.x*256 + threadIdx.x;
  int t = i & (TT-1), b = i >> 10;
  float s = 0.f;
  #pragma unroll
  for (int dd = -2; dd <= 2; dd++){
    int tt = t + dd;
    if (tt >= 0 && tt < TT) s += vin[(b << 10) + tt];
  }
  s *= 0.2f;
  float vv = 0.7f*vin[i] + 0.3f*s;
  vout[i] = (vv > 0.3f) ? vv : 0.1f*vv;
}

// ---- final: out = x1 + mlp*sig(g)*(1+0.1*tanh(ca2)) * vit ----
__global__ __launch_bounds__(256) void final_k(const float* __restrict__ x1,
    const float* __restrict__ mlpraw, const float* __restrict__ g,
    const float* __restrict__ ca2, const float* __restrict__ vsm,
    float* __restrict__ out){
  size_t i = (size_t)blockIdx.x*256 + threadIdx.x;
  size_t bt = i >> 10;
  float mlp = mlpraw[i] * sigf(g[i]) * (1.f + 0.1f*tanhf(ca2[i]));
  out[i] = x1[i] + mlp * vsm[bt];
}

extern "C" void kernel_launch(void* const* d_in, const int* in_sizes, int n_in,
                              void* d_out, int out_size, void* d_ws, size_t ws_size,
                              hipStream_t stream) {
  (void)in_sizes; (void)n_in; (void)out_size; (void)ws_size;
  const float* x     = (const float*)d_in[0];
  const float* ve    = (const float*)d_in[1];
  const float* cs    = (const float*)d_in[2];
  const float* sn    = (const float*)d_in[3];
  const float* pa    = (const float*)d_in[4];
  const float* w_q   = (const float*)d_in[5];
  const float* w_k   = (const float*)d_in[6];
  const float* w_v   = (const float*)d_in[7];
  const float* w_o   = (const float*)d_in[8];
  const float* w_vg  = (const float*)d_in[9];
  const float* rfw   = (const float*)d_in[10];
  const float* ralp  = (const float*)d_in[11];
  const float* capi  = (const float*)d_in[12];
  const float* cacw  = (const float*)d_in[13];
  const float* capo  = (const float*)d_in[14];
  const float* ffin  = (const float*)d_in[15];
  const float* ffcw  = (const float*)d_in[16];
  const float* ffout = (const float*)d_in[17];
  const float* ffgt  = (const float*)d_in[18];
  const float* vw1   = (const float*)d_in[19];
  const float* vw2   = (const float*)d_in[20];

  // ---- workspace layout (lifetimes disjoint where aliased), 232 MiB total ----
  const size_t M4  = (size_t)BB*TT*CC;      // 4,194,304 elements
  const size_t MB1 = 1ull << 20;
  char* WSB = (char*)d_ws;

  unsigned short* xnh = (unsigned short*)WSB;          //  0..16MiB: xn/xm bf16 pair
  unsigned short* xnl = xnh + M4;
  float* ca1 = (float*)WSB;                            //  (alias, after xn consumed)
  float* qb  = (float*)(WSB + 16*MB1);                 // 16..32: q fp32 (later ffn gate)
  float* kb  = (float*)(WSB + 32*MB1);                 // 32..36: k fp32
  unsigned short* ffgp = (unsigned short*)(WSB + 32*MB1); // (alias after fattn: ffgt pair)
  float* vb  = (float*)(WSB + 36*MB1);                 // 36..40: v fp32
  float* cah = (float*)(WSB + 36*MB1);                 // (alias after fattn)
  float* cag = cah + (size_t)BB*TT*CAD;
  float* vtb = cag + (size_t)BB*TT*CAD;
  float* vsm = vtb + (size_t)BB*TT;
  float* ao  = (float*)(WSB + 40*MB1);                 // 40..56: attn_out (later mlp raw)
  float* x1b = (float*)(WSB + 56*MB1);                 // 56..72: x1 fp32 (early: y pair)
  unsigned short* yh = (unsigned short*)x1b;
  unsigned short* yl = yh + M4;
  float* hb  = (float*)(WSB + 72*MB1);                 // 72..136: h fp32 (conv input)
  float* h2  = (float*)(WSB + 136*MB1);                // 136..200: h bf16 pair (early: qkvo weight pairs, late: ca2)
  unsigned short* hh = (unsigned short*)h2;
  unsigned short* hl = hh + 4*M4;
  unsigned short* wqp = (unsigned short*)(WSB + 136*MB1);
  unsigned short* wkp = (unsigned short*)(WSB + 140*MB1);
  unsigned short* wvp = (unsigned short*)(WSB + 141*MB1);
  unsigned short* wop = (unsigned short*)(WSB + 142*MB1);
  float* ca2 = h2;
  unsigned short* ffip = (unsigned short*)(WSB + 200*MB1); // 200..216: ffn_in pair
  unsigned short* ffop = (unsigned short*)(WSB + 216*MB1); // 216..232: ffn_out pair

  const int BT = BB*TT;                     // 4096
  const int WQN = NH*HD*CC;                 // 1,048,576
  const int WKN = NKV*HD*CC;                // 262,144

  split_k<<<WQN/1024, 256, 0, stream>>>(w_q, wqp, wqp + WQN, WQN/4);
  split_k<<<WKN/1024, 256, 0, stream>>>(w_k, wkp, wkp + WKN, WKN/4);
  split_k<<<WKN/1024, 256, 0, stream>>>(w_v, wvp, wvp + WKN, WKN/4);
  split_k<<<WQN/1024, 256, 0, stream>>>(w_o, wop, wop + WQN, WQN/4);
  split_k<<<M4/1024, 256, 0, stream>>>(ffin, ffip, ffip + M4, (int)(M4/4));
  split_k<<<M4/1024, 256, 0, stream>>>(ffout, ffop, ffop + M4, (int)(M4/4));

  rmsnorm_pair_k<<<BT, 256, 0, stream>>>(x, xnh, xnl);
  gemm3_k<0><<<dim3(8, 32), 256, 0, stream>>>(xnh, xnl, wqp, wqp + WQN, qb, BT, 1024, 1024);
  gemm3_k<0><<<dim3(2, 32), 256, 0, stream>>>(xnh, xnl, wkp, wkp + WKN, kb, BT, 256, 1024);
  gemm3_k<0><<<dim3(2, 32), 256, 0, stream>>>(xnh, xnl, wvp, wvp + WKN, vb, BT, 256, 1024);
  rope_rms_k<<<BT*NH, 64, 0, stream>>>(qb, cs, sn, NH);
  rope_rms_k<<<BT*NKV, 64, 0, stream>>>(kb, cs, sn, NKV);
  gatev_k<<<BT, 256, 0, stream>>>(vb, xnh, xnl, ve, w_vg);
  fattn_k<<<dim3(TT/TQ, NH, BB), 256, 0, stream>>>(qb, kb, vb, pa, rfw, ralp, yh, yl);
  gemm3_k<0><<<dim3(8, 32), 256, 0, stream>>>(yh, yl, wop, wop + WQN, ao, BT, 1024, 1024);
  split_k<<<WQN/1024, 256, 0, stream>>>(ffgt, ffgp, ffgp + WQN, WQN/4);
  cain_k<<<BT, 256, 0, stream>>>(x, capi, cah);
  caconv_k<<<BT*CAD/256, 256, 0, stream>>>(cah, cacw, cag);
  caout_k<<<BT, 256, 0, stream>>>(cag, capo, ca1);
  x1_k<<<BT*CC/256, 256, 0, stream>>>(x, ao, ca1, x1b);
  rmsnorm_pair_k<<<BT, 256, 0, stream>>>(x1b, xnh, xnl);      // xm pair
  gemm3_k<1><<<dim3(32, 32), 256, 0, stream>>>(xnh, xnl, ffip, ffip + M4, hb, BT, FFNH, 1024);
  ffnconv4_k<<<dim3(FFNH/256, TT/64, BB), 256, 0, stream>>>(hb, ffcw, hh, hl);
  gemm3_k<0><<<dim3(8, 32), 256, 0, stream>>>(xnh, xnl, ffgp, ffgp + WQN, qb, BT, 1024, 1024);
  gemm3_k<0><<<dim3(8, 32), 256, 0, stream>>>(hh, hl, ffop, ffop + M4, ao, BT, 1024, FFNH);
  cain_k<<<BT, 256, 0, stream>>>(x1b, capi, cah);
  caconv_k<<<BT*CAD/256, 256, 0, stream>>>(cah, cacw, cag);
  caout_k<<<BT, 256, 0, stream>>>(cag, capo, ca2);
  vit_k<<<BT, 256, 0, stream>>>(x1b, vw1, vw2, vtb);
  vitsm_k<<<BT/256, 256, 0, stream>>>(vtb, vsm);
  final_k<<<BT*CC/256, 256, 0, stream>>>(x1b, ao, qb, ca2, vsm, (float*)d_out);
}

// Round 5
// 1573.646 us; speedup vs baseline: 1.7624x; 1.1840x over previous
//
#include <hip/hip_runtime.h>

// ---- constants ----
#define BB 4
#define TT 1024
#define CC 1024
#define NH 16
#define NKV 4
#define HD 64
#define FFNH 4096
#define CAD 32
#define TQ 64
#define TK 64

typedef short bf16x8 __attribute__((ext_vector_type(8)));
typedef float f32x4  __attribute__((ext_vector_type(4)));

#define AS1 __attribute__((address_space(1)))
#define AS3 __attribute__((address_space(3)))

__device__ __forceinline__ float sigf(float x){ return 1.f/(1.f+__expf(-x)); }
__device__ __forceinline__ float geluf(float x){ return 0.5f*x*(1.f+erff(x*0.70710678118654752f)); }

// fp32 -> bf16 (round-to-nearest-even), and back
__device__ __forceinline__ unsigned short f2bf(float f){
  unsigned int u = __float_as_uint(f);
  u += 0x7fffu + ((u >> 16) & 1u);
  return (unsigned short)(u >> 16);
}
__device__ __forceinline__ float bf2f(unsigned short h){
  return __uint_as_float(((unsigned int)h) << 16);
}

// ---- rmsnorm over last dim (1024), emitting bf16 hi/lo pair ----
__global__ __launch_bounds__(256) void rmsnorm_pair_k(const float* __restrict__ x,
    unsigned short* __restrict__ oh, unsigned short* __restrict__ ol){
  int row = blockIdx.x;
  const float* xr = x + (size_t)row * CC;
  float v[4]; float ss = 0.f;
  #pragma unroll
  for (int i = 0; i < 4; i++){ v[i] = xr[threadIdx.x + 256*i]; ss += v[i]*v[i]; }
  #pragma unroll
  for (int off = 1; off < 64; off <<= 1) ss += __shfl_xor(ss, off);
  __shared__ float red[4];
  if ((threadIdx.x & 63) == 0) red[threadIdx.x >> 6] = ss;
  __syncthreads();
  float tot = red[0]+red[1]+red[2]+red[3];
  float rs = rsqrtf(tot * (1.f/CC) + 1e-6f);
  size_t base = (size_t)row * CC;
  #pragma unroll
  for (int i = 0; i < 4; i++){
    float r = v[i]*rs;
    unsigned short h = f2bf(r);
    oh[base + threadIdx.x + 256*i] = h;
    ol[base + threadIdx.x + 256*i] = f2bf(r - bf2f(h));
  }
}

// ---- generic fp32 -> bf16 hi/lo splitter (for weights) ----
__global__ __launch_bounds__(256) void split_k(const float* __restrict__ in,
    unsigned short* __restrict__ hi, unsigned short* __restrict__ lo, int n4){
  int i = blockIdx.x*256 + threadIdx.x;
  if (i >= n4) return;
  float4 v = ((const float4*)in)[i];
  unsigned short h0 = f2bf(v.x), h1 = f2bf(v.y), h2v = f2bf(v.z), h3 = f2bf(v.w);
  ushort4 hv = { h0, h1, h2v, h3 };
  ushort4 lv = { f2bf(v.x - bf2f(h0)), f2bf(v.y - bf2f(h1)),
                 f2bf(v.z - bf2f(h2v)), f2bf(v.w - bf2f(h3)) };
  ((ushort4*)hi)[i] = hv;
  ((ushort4*)lo)[i] = lv;
}

// ---- bf16x3 MFMA GEMM (verified round 2) ----
template<int EPI>
__global__ __launch_bounds__(256) void gemm3_k(
    const unsigned short* __restrict__ Ah, const unsigned short* __restrict__ Al,
    const unsigned short* __restrict__ Wh, const unsigned short* __restrict__ Wl,
    float* __restrict__ C, int M, int N, int K)
{
  __shared__ unsigned short AhS[128*32];
  __shared__ unsigned short AlS[128*32];
  __shared__ unsigned short WhS[128*32];
  __shared__ unsigned short WlS[128*32];
  int tid  = threadIdx.x;
  int lane = tid & 63, wave = tid >> 6;
  int wr = wave >> 1, wc = wave & 1;
  int m0 = blockIdx.y << 7, n0 = blockIdx.x << 7;
  int lr = lane & 15, lc = lane >> 4;

  int offA[4], offB[4];
  #pragma unroll
  for (int m = 0; m < 4; m++){
    int row = wr*64 + m*16 + lr;
    offA[m] = row*64 + ((lc ^ ((row >> 1) & 3)) << 4);
  }
  #pragma unroll
  for (int n = 0; n < 4; n++){
    int row = wc*64 + n*16 + lr;
    offB[n] = row*64 + ((lc ^ ((row >> 1) & 3)) << 4);
  }

  f32x4 acc[4][4] = {};

  for (int k0 = 0; k0 < K; k0 += 32){
    __syncthreads();
    {
      const unsigned short* srcs[4] = { Ah, Al, Wh, Wl };
      unsigned short* dsts[4] = { AhS, AlS, WhS, WlS };
      int rb[4] = { m0, m0, n0, n0 };
      #pragma unroll
      for (int tle = 0; tle < 4; tle++){
        #pragma unroll
        for (int i = 0; i < 2; i++){
          int s = i*256 + tid;
          int row = s >> 2;
          int c = (s & 3) ^ ((row >> 1) & 3);
          const unsigned short* gp = srcs[tle] + (size_t)(rb[tle] + row)*K + (k0 + c*8);
          unsigned short* lp = dsts[tle] + i*2048 + wave*512;
          __builtin_amdgcn_global_load_lds((const AS1 void*)gp, (AS3 void*)lp, 16, 0, 0);
        }
      }
    }
    __syncthreads();

    bf16x8 ah[4], al[4], bh[4], bl[4];
    #pragma unroll
    for (int m = 0; m < 4; m++){
      ah[m] = *(const bf16x8*)((const char*)AhS + offA[m]);
      al[m] = *(const bf16x8*)((const char*)AlS + offA[m]);
    }
    #pragma unroll
    for (int n = 0; n < 4; n++){
      bh[n] = *(const bf16x8*)((const char*)WhS + offB[n]);
      bl[n] = *(const bf16x8*)((const char*)WlS + offB[n]);
    }
    #pragma unroll
    for (int m = 0; m < 4; m++){
      #pragma unroll
      for (int n = 0; n < 4; n++){
        acc[m][n] = __builtin_amdgcn_mfma_f32_16x16x32_bf16(al[m], bh[n], acc[m][n], 0, 0, 0);
        acc[m][n] = __builtin_amdgcn_mfma_f32_16x16x32_bf16(ah[m], bl[n], acc[m][n], 0, 0, 0);
        acc[m][n] = __builtin_amdgcn_mfma_f32_16x16x32_bf16(ah[m], bh[n], acc[m][n], 0, 0, 0);
      }
    }
  }

  #pragma unroll
  for (int m = 0; m < 4; m++){
    int r0 = m0 + wr*64 + m*16 + lc*4;
    #pragma unroll
    for (int n = 0; n < 4; n++){
      int col = n0 + wc*64 + n*16 + lr;
      #pragma unroll
      for (int r = 0; r < 4; r++){
        float z = acc[m][n][r];
        if (EPI == 1){ z = fmaxf(z, 0.f); z = z*z; }
        C[(size_t)(r0 + r)*N + col] = z;
      }
    }
  }
}

// ---- rope + head-rmsnorm * 1.2 ----
__global__ __launch_bounds__(64) void rope_rms_k(float* __restrict__ q,
    const float* __restrict__ cs, const float* __restrict__ sn, int nh){
  int idx = blockIdx.x;
  int t = (idx / nh) & (TT-1);
  float* qp = q + (size_t)idx * HD;
  int d = threadIdx.x;
  int dl = d & 31;
  float c = cs[t*32 + dl], s = sn[t*32 + dl];
  float v0 = qp[d];
  float vp = qp[(d < 32) ? d + 32 : d - 32];
  float r = (d < 32) ? (v0*c + vp*s) : (v0*c - vp*s);
  float ss = r*r;
  #pragma unroll
  for (int off = 1; off < 64; off <<= 1) ss += __shfl_xor(ss, off);
  float rs = rsqrtf(ss*(1.f/HD) + 1e-6f) * 1.2f;
  qp[d] = r*rs;
}

// ---- v += 3*sigmoid(xn[:,:12] @ wg^T) * ve ----
__global__ __launch_bounds__(256) void gatev_k(float* __restrict__ v,
    const unsigned short* __restrict__ xnh, const unsigned short* __restrict__ xnl,
    const float* __restrict__ ve, const float* __restrict__ wg){
  int bt = blockIdx.x;
  int tid = threadIdx.x;
  int kv = tid >> 6;
  float s = 0.f;
  #pragma unroll
  for (int j = 0; j < 12; j++){
    float xv = bf2f(xnh[(size_t)bt*CC + j]) + bf2f(xnl[(size_t)bt*CC + j]);
    s += xv*wg[kv*12+j];
  }
  float gate = 3.f * sigf(s);
  size_t i = (size_t)bt*(NKV*HD) + tid;
  v[i] += gate * ve[i];
}

// ---- MFMA flash attention (S^T trick), occupancy-tuned (round 5):
//      Q frags direct global->reg; K bf16 hi/lo LDS; V bf16-hi LDS; P bf16-hi LDS.
//      LDS = 42.3 KB -> 3 blocks/CU. Fused refine conv from bf16 pa tile. ----
__global__ __launch_bounds__(256) void fattn_k(
    const float* __restrict__ q, const float* __restrict__ k, const float* __restrict__ v,
    const float* __restrict__ pa, const float* __restrict__ rw,
    const float* __restrict__ alphap,
    unsigned short* __restrict__ yh, unsigned short* __restrict__ yl)
{
  int qt = blockIdx.x;
  int h  = blockIdx.y;
  int b  = blockIdx.z;
  int kv = h >> 2;
  int t0 = qt * TQ;
  int tid = threadIdx.x;
  int lane = tid & 63, w = tid >> 6;
  int dl = lane & 15, gq = lane >> 4;

  __shared__ __align__(16) unsigned short Kh[4096], Kl[4096];   // [64 k][64 d] swz, bf16 pair
  __shared__ __align__(16) unsigned short Vh[64][68];           // [k][d] bf16 hi
  __shared__ __align__(16) unsigned short SBs[66*68];           // pa tile bf16, rows t0-1..t0+64
  __shared__ __align__(16) unsigned short Ph[4][1024];          // per-wave P [16 q][64 k] swz, hi

  // Q fragments direct from global (lane's q row = 16w+dl)
  bf16x8 qfh[2], qfl[2];
  {
    const float* qrow = q + (((size_t)(b*TT + t0 + 16*w + dl))*NH + h)*HD;
    #pragma unroll
    for (int ks = 0; ks < 2; ks++){
      float4 a = *(const float4*)(qrow + (gq+4*ks)*8);
      float4 bq = *(const float4*)(qrow + (gq+4*ks)*8 + 4);
      float vv[8] = {a.x,a.y,a.z,a.w,bq.x,bq.y,bq.z,bq.w};
      #pragma unroll
      for (int i = 0; i < 8; i++){
        unsigned short hv = f2bf(vv[i]);
        qfh[ks][i] = (short)hv;
        qfl[ks][i] = (short)f2bf(vv[i] - bf2f(hv));
      }
    }
  }

  float alpha = *alphap;
  float w9[9];
  #pragma unroll
  for (int j = 0; j < 9; j++) w9[j] = rw[h*9+j]*alpha;

  float m_i = -1e30f, l_i = 0.f;
  f32x4 acc_o[4] = {};
  int ql = 16*w + dl;      // lane's q (local in tile)

  for (int kt = 0; kt <= qt; kt++){
    int k0 = kt*TK;
    __syncthreads();   // prior tile's K/V/SB reads complete
    // stage K (bf16 pair, swizzled) + V (bf16 hi, [k][d] stride 68)
    #pragma unroll
    for (int it = 0; it < 4; it++){
      int s = it*256 + tid;
      int r = s >> 4, d4 = (s & 15) << 2;
      const float* kp = k + (((size_t)(b*TT + k0 + r))*NKV + kv)*HD + d4;
      float4 val = *(const float4*)kp;
      ushort4 hv = { f2bf(val.x), f2bf(val.y), f2bf(val.z), f2bf(val.w) };
      ushort4 lv = { f2bf(val.x - bf2f(hv.x)), f2bf(val.y - bf2f(hv.y)),
                     f2bf(val.z - bf2f(hv.z)), f2bf(val.w - bf2f(hv.w)) };
      int idx = r*64 + (((d4 >> 3) ^ (r & 7)) << 3) + (d4 & 7);
      *(ushort4*)&Kh[idx] = hv;
      *(ushort4*)&Kl[idx] = lv;
      const float* vp = v + (((size_t)(b*TT + k0 + r))*NKV + kv)*HD + d4;
      float4 vval = *(const float4*)vp;
      ushort4 vh4 = { f2bf(vval.x), f2bf(vval.y), f2bf(vval.z), f2bf(vval.w) };
      *(ushort4*)&Vh[r][d4] = vh4;
    }
    // stage pa tile: float4 body (always in-bounds), scalar halo (bounds-checked)
    #pragma unroll
    for (int it = 0; it < 4; it++){
      int e = it*256 + tid;
      int r = e >> 4, c4 = (e & 15) << 2;
      const float* pp = pa + ((size_t)(b*NH + h)*TT + (t0 + r))*TT + (k0 + c4);
      float4 pv = *(const float4*)pp;
      unsigned short* sp = &SBs[(r+1)*68 + (c4+1)];
      sp[0] = f2bf(pv.x); sp[1] = f2bf(pv.y); sp[2] = f2bf(pv.z); sp[3] = f2bf(pv.w);
    }
    for (int e = tid; e < 260; e += 256){
      int li, lj;
      if (e < 132){ li = (e < 66) ? 0 : 65; lj = (e < 66) ? e : e - 66; }
      else { int idx = e - 132; li = 1 + (idx & 63); lj = (idx >> 6) ? 65 : 0; }
      int gr = t0 - 1 + li, gc = k0 - 1 + lj;
      float pv = 0.f;
      if (gr >= 0 && gr < TT && gc >= 0 && gc < TT)
        pv = pa[((size_t)(b*NH + h)*TT + gr)*TT + gc];
      SBs[li*68 + lj] = f2bf(pv);
    }
    __syncthreads();

    // S^T = K·Q^T  (rows = k, cols = q), bf16x3
    f32x4 acc_s[4] = {};
    __builtin_amdgcn_s_setprio(1);
    #pragma unroll
    for (int ks = 0; ks < 2; ks++){
      #pragma unroll
      for (int kf = 0; kf < 4; kf++){
        int row = 16*kf + dl;
        int idx = row*64 + (((gq + 4*ks) ^ (row & 7)) << 3);
        bf16x8 kh_ = *(const bf16x8*)&Kh[idx];
        bf16x8 kl_ = *(const bf16x8*)&Kl[idx];
        acc_s[kf] = __builtin_amdgcn_mfma_f32_16x16x32_bf16(kl_, qfh[ks], acc_s[kf], 0, 0, 0);
        acc_s[kf] = __builtin_amdgcn_mfma_f32_16x16x32_bf16(kh_, qfl[ks], acc_s[kf], 0, 0, 0);
        acc_s[kf] = __builtin_amdgcn_mfma_f32_16x16x32_bf16(kh_, qfh[ks], acc_s[kf], 0, 0, 0);
      }
    }
    __builtin_amdgcn_s_setprio(0);

    // conv + scale + causal mask; lane elem (k = 16kf+4gq+reg, q = ql)
    #pragma unroll
    for (int kf = 0; kf < 4; kf++){
      int kb = 16*kf + 4*gq;
      float cv0=0.f, cv1=0.f, cv2=0.f, cv3=0.f;
      #pragma unroll
      for (int dy = 0; dy < 3; dy++){
        const unsigned short* rp = &SBs[(ql + dy)*68 + kb];
        float u0 = bf2f(rp[0]), u1 = bf2f(rp[1]), u2 = bf2f(rp[2]),
              u3 = bf2f(rp[3]), u4 = bf2f(rp[4]), u5 = bf2f(rp[5]);
        float wa = w9[dy*3+0], wb = w9[dy*3+1], wcq = w9[dy*3+2];
        cv0 += u0*wa + u1*wb + u2*wcq;
        cv1 += u1*wa + u2*wb + u3*wcq;
        cv2 += u2*wa + u3*wb + u4*wcq;
        cv3 += u3*wa + u4*wb + u5*wcq;
      }
      int grow = t0 + ql;
      float s0 = acc_s[kf][0]*0.125f + cv0; if (k0 + kb + 0 > grow) s0 = -1e30f;
      float s1 = acc_s[kf][1]*0.125f + cv1; if (k0 + kb + 1 > grow) s1 = -1e30f;
      float s2 = acc_s[kf][2]*0.125f + cv2; if (k0 + kb + 2 > grow) s2 = -1e30f;
      float s3 = acc_s[kf][3]*0.125f + cv3; if (k0 + kb + 3 > grow) s3 = -1e30f;
      acc_s[kf][0] = s0; acc_s[kf][1] = s1; acc_s[kf][2] = s2; acc_s[kf][3] = s3;
    }

    // online softmax over k (lane's q fixed): local 16 + cross-g shfl
    float rm = -1e30f;
    #pragma unroll
    for (int kf = 0; kf < 4; kf++){
      rm = fmaxf(rm, fmaxf(fmaxf(acc_s[kf][0], acc_s[kf][1]),
                           fmaxf(acc_s[kf][2], acc_s[kf][3])));
    }
    rm = fmaxf(rm, __shfl_xor(rm, 16));
    rm = fmaxf(rm, __shfl_xor(rm, 32));
    float mn = fmaxf(m_i, rm);
    float sc = __expf(m_i - mn);
    m_i = mn;
    float rs = 0.f;
    #pragma unroll
    for (int kf = 0; kf < 4; kf++){
      float p0 = __expf(acc_s[kf][0] - mn);
      float p1 = __expf(acc_s[kf][1] - mn);
      float p2 = __expf(acc_s[kf][2] - mn);
      float p3 = __expf(acc_s[kf][3] - mn);
      rs += p0 + p1 + p2 + p3;
      ushort4 hv = { f2bf(p0), f2bf(p1), f2bf(p2), f2bf(p3) };
      int kbl = 16*kf + 4*gq;
      int idx = dl*64 + ((((kbl >> 3)) ^ (dl & 7)) << 3) + (kbl & 7);
      *(ushort4*)&Ph[w][idx] = hv;
    }
    rs += __shfl_xor(rs, 16);
    rs += __shfl_xor(rs, 32);
    l_i = l_i*sc + rs;

    // rescale O (O rows q = 4gq+reg -> fetch sc from lane 4gq+reg)
    float scR0 = __shfl(sc, gq*4 + 0);
    float scR1 = __shfl(sc, gq*4 + 1);
    float scR2 = __shfl(sc, gq*4 + 2);
    float scR3 = __shfl(sc, gq*4 + 3);
    #pragma unroll
    for (int nf = 0; nf < 4; nf++){
      acc_o[nf][0] *= scR0; acc_o[nf][1] *= scR1;
      acc_o[nf][2] *= scR2; acc_o[nf][3] *= scR3;
    }

    // O += P·V  (P hi from own wave's LDS; V hi from LDS, scalar gather)
    #pragma unroll
    for (int ks = 0; ks < 2; ks++){
      int idxp = dl*64 + (((gq + 4*ks) ^ (dl & 7)) << 3);
      bf16x8 pfh = *(const bf16x8*)&Ph[w][idxp];
      __builtin_amdgcn_s_setprio(1);
      #pragma unroll
      for (int nf = 0; nf < 4; nf++){
        bf16x8 vh_;
        #pragma unroll
        for (int i = 0; i < 8; i++)
          vh_[i] = (short)Vh[ks*32 + gq*8 + i][16*nf + dl];
        acc_o[nf] = __builtin_amdgcn_mfma_f32_16x16x32_bf16(pfh, vh_, acc_o[nf], 0, 0, 0);
      }
      __builtin_amdgcn_s_setprio(0);
    }
  }

  // epilogue: O rows q = 16*w + 4*gq + reg, cols d = 16nf+dl
  float li0 = __shfl(l_i, gq*4 + 0);
  float li1 = __shfl(l_i, gq*4 + 1);
  float li2 = __shfl(l_i, gq*4 + 2);
  float li3 = __shfl(l_i, gq*4 + 3);
  float inv0 = 1.f/li0, inv1 = 1.f/li1, inv2 = 1.f/li2, inv3 = 1.f/li3;
  #pragma unroll
  for (int nf = 0; nf < 4; nf++){
    int dcol = 16*nf + dl;
    #pragma unroll
    for (int reg = 0; reg < 4; reg++){
      float invv = (reg == 0) ? inv0 : (reg == 1) ? inv1 : (reg == 2) ? inv2 : inv3;
      float val = acc_o[nf][reg] * invv;
      size_t bix = (((size_t)(b*TT + t0 + 16*w + gq*4 + reg))*NH + h)*HD + dcol;
      unsigned short hv = f2bf(val);
      yh[bix] = hv;
      yl[bix] = f2bf(val - bf2f(hv));
    }
  }
}

// ---- CA: in-projection (K=1024 -> 32) ----
__global__ __launch_bounds__(256) void cain_k(const float* __restrict__ x,
    const float* __restrict__ pi, float* __restrict__ out){
  int bt = blockIdx.x;
  __shared__ float xs[CC];
  __shared__ float pr[8][33];
  for (int i = threadIdx.x; i < CC; i += 256) xs[i] = x[(size_t)bt*CC + i];
  __syncthreads();
  int d = threadIdx.x & 31, sl = threadIdx.x >> 5;
  const float* pip = pi + (size_t)d*CC + sl*128;
  float s = 0.f;
  #pragma unroll 8
  for (int i = 0; i < 128; i++) s += xs[sl*128+i]*pip[i];
  pr[sl][d] = s;
  __syncthreads();
  if (threadIdx.x < 32){
    float tot = 0.f;
    #pragma unroll
    for (int j = 0; j < 8; j++) tot += pr[j][threadIdx.x];
    out[(size_t)bt*CAD + threadIdx.x] = tot;
  }
}

// ---- CA: depthwise conv over T + exact gelu ----
__global__ __launch_bounds__(256) void caconv_k(const float* __restrict__ hin,
    const float* __restrict__ cw, float* __restrict__ gout){
  int i = blockIdx.x*256 + threadIdx.x;
  int d = i & 31;
  int bt = i >> 5;
  int t = bt & (TT-1);
  float cc = hin[i];
  float hm = (t > 0)      ? hin[i-32] : 0.f;
  float hp = (t < TT-1)   ? hin[i+32] : 0.f;
  float hc = cc + 0.1f*(hm*cw[d*3] + cc*cw[d*3+1] + hp*cw[d*3+2]);
  gout[i] = geluf(hc);
}

// ---- CA: out-projection (K=32 -> 1024) ----
__global__ __launch_bounds__(256) void caout_k(const float* __restrict__ g,
    const float* __restrict__ po, float* __restrict__ out){
  int bt = blockIdx.x;
  __shared__ float gs[CAD];
  if (threadIdx.x < CAD) gs[threadIdx.x] = g[(size_t)bt*CAD + threadIdx.x];
  __syncthreads();
  for (int c = threadIdx.x; c < CC; c += 256){
    const float* pp = po + (size_t)c*CAD;
    float s = 0.f;
    #pragma unroll
    for (int d2 = 0; d2 < CAD; d2++) s += gs[d2]*pp[d2];
    out[(size_t)bt*CC + c] = s;
  }
}

// ---- x1 = x + attn_out * (1 + 0.1*tanh(ca1)) ----
__global__ __launch_bounds__(256) void x1_k(const float* __restrict__ x,
    const float* __restrict__ ao, const float* __restrict__ ca1, float* __restrict__ x1){
  size_t i = (size_t)blockIdx.x*256 + threadIdx.x;
  x1[i] = x[i] + ao[i] * (1.f + 0.1f*tanhf(ca1[i]));
}

// ---- fused 4-pass FFN depthwise conv (register cascade), bf16 pair out ----
__global__ __launch_bounds__(256) void ffnconv4_k(const float* __restrict__ hin,
    const float* __restrict__ cw, unsigned short* __restrict__ hh, unsigned short* __restrict__ hl){
  int c  = blockIdx.x*256 + threadIdx.x;     // channel
  int ta = blockIdx.y*64;                    // t-chunk start
  int b  = blockIdx.z;
  float w0 = cw[c*3+0], w1 = cw[c*3+1], w2 = cw[c*3+2];
  size_t base = (size_t)b*TT*FFNH + c;
  float i0=0.f,i1=0.f,i2=0.f;
  float a0=0.f,a1=0.f,a2=0.f;
  float b0=0.f,b1=0.f,b2=0.f;
  float c0=0.f,c1=0.f,c2=0.f;
  for (int t = ta-4; t <= ta+67; t++){
    float iv = 0.f;
    if (t >= 0 && t < TT) iv = hin[base + (size_t)t*FFNH];
    i0 = i1; i1 = i2; i2 = iv;
    float s1 = i1 + 0.1f*(i0*w0 + i1*w1 + i2*w2);
    if (t-1 < 0 || t-1 >= TT) s1 = 0.f;
    a0 = a1; a1 = a2; a2 = s1;
    float s2 = a1 + 0.1f*(a0*w0 + a1*w1 + a2*w2);
    if (t-2 < 0 || t-2 >= TT) s2 = 0.f;
    b0 = b1; b1 = b2; b2 = s2;
    float s3 = b1 + 0.1f*(b0*w0 + b1*w1 + b2*w2);
    if (t-3 < 0 || t-3 >= TT) s3 = 0.f;
    c0 = c1; c1 = c2; c2 = s3;
    float s4 = c1 + 0.1f*(c0*w0 + c1*w1 + c2*w2);
    int t4 = t-4;
    if (t4 >= ta){
      size_t oix = base + (size_t)t4*FFNH;
      unsigned short hv = f2bf(s4);
      hh[oix] = hv;
      hl[oix] = f2bf(s4 - bf2f(hv));
    }
  }
}

// ---- vit scalar gate ----
__global__ __launch_bounds__(256) void vit_k(const float* __restrict__ x1,
    const float* __restrict__ w1, const float* __restrict__ w2,
    float* __restrict__ vout){
  int bt = blockIdx.x;
  __shared__ float xs[CC];
  __shared__ float pr[8][33];
  __shared__ float g32[32];
  for (int i = threadIdx.x; i < CC; i += 256) xs[i] = x1[(size_t)bt*CC + i];
  __syncthreads();
  int d = threadIdx.x & 31, sl = threadIdx.x >> 5;
  const float* wp = w1 + (size_t)d*CC + sl*128;
  float s = 0.f;
  #pragma unroll 8
  for (int i = 0; i < 128; i++) s += xs[sl*128+i]*wp[i];
  pr[sl][d] = s;
  __syncthreads();
  if (threadIdx.x < 32){
    float tot = 0.f;
    #pragma unroll
    for (int j = 0; j < 8; j++) tot += pr[j][threadIdx.x];
    g32[threadIdx.x] = geluf(tot);
  }
  __syncthreads();
  if (threadIdx.x == 0){
    float s2 = 0.f;
    #pragma unroll
    for (int d2 = 0; d2 < 32; d2++) s2 += g32[d2]*w2[d2];
    vout[bt] = sigf(s2);
  }
}

// ---- vit smoothing + threshold ----
__global__ __launch_bounds__(256) void vitsm_k(const float* __restrict__ vin, float* __restrict__ vout){
  int i = blockIdx.x*256 + threadIdx.x;
  int t = i & (TT-1), b = i >> 10;
  float s = 0.f;
  #pragma unroll
  for (int dd = -2; dd <= 2; dd++){
    int tt = t + dd;
    if (tt >= 0 && tt < TT) s += vin[(b << 10) + tt];
  }
  s *= 0.2f;
  float vv = 0.7f*vin[i] + 0.3f*s;
  vout[i] = (vv > 0.3f) ? vv : 0.1f*vv;
}

// ---- final: out = x1 + mlp*sig(g)*(1+0.1*tanh(ca2)) * vit ----
__global__ __launch_bounds__(256) void final_k(const float* __restrict__ x1,
    const float* __restrict__ mlpraw, const float* __restrict__ g,
    const float* __restrict__ ca2, const float* __restrict__ vsm,
    float* __restrict__ out){
  size_t i = (size_t)blockIdx.x*256 + threadIdx.x;
  size_t bt = i >> 10;
  float mlp = mlpraw[i] * sigf(g[i]) * (1.f + 0.1f*tanhf(ca2[i]));
  out[i] = x1[i] + mlp * vsm[bt];
}

extern "C" void kernel_launch(void* const* d_in, const int* in_sizes, int n_in,
                              void* d_out, int out_size, void* d_ws, size_t ws_size,
                              hipStream_t stream) {
  (void)in_sizes; (void)n_in; (void)out_size; (void)ws_size;
  const float* x     = (const float*)d_in[0];
  const float* ve    = (const float*)d_in[1];
  const float* cs    = (const float*)d_in[2];
  const float* sn    = (const float*)d_in[3];
  const float* pa    = (const float*)d_in[4];
  const float* w_q   = (const float*)d_in[5];
  const float* w_k   = (const float*)d_in[6];
  const float* w_v   = (const float*)d_in[7];
  const float* w_o   = (const float*)d_in[8];
  const float* w_vg  = (const float*)d_in[9];
  const float* rfw   = (const float*)d_in[10];
  const float* ralp  = (const float*)d_in[11];
  const float* capi  = (const float*)d_in[12];
  const float* cacw  = (const float*)d_in[13];
  const float* capo  = (const float*)d_in[14];
  const float* ffin  = (const float*)d_in[15];
  const float* ffcw  = (const float*)d_in[16];
  const float* ffout = (const float*)d_in[17];
  const float* ffgt  = (const float*)d_in[18];
  const float* vw1   = (const float*)d_in[19];
  const float* vw2   = (const float*)d_in[20];

  // ---- workspace layout (lifetimes disjoint where aliased), 232 MiB total ----
  const size_t M4  = (size_t)BB*TT*CC;      // 4,194,304 elements
  const size_t MB1 = 1ull << 20;
  char* WSB = (char*)d_ws;

  unsigned short* xnh = (unsigned short*)WSB;          //  0..16MiB: xn/xm bf16 pair
  unsigned short* xnl = xnh + M4;
  float* ca1 = (float*)WSB;                            //  (alias, after xn consumed)
  float* qb  = (float*)(WSB + 16*MB1);                 // 16..32: q fp32 (later ffn gate)
  float* kb  = (float*)(WSB + 32*MB1);                 // 32..36: k fp32
  unsigned short* ffgp = (unsigned short*)(WSB + 32*MB1); // (alias after fattn: ffgt pair)
  float* vb  = (float*)(WSB + 36*MB1);                 // 36..40: v fp32
  float* cah = (float*)(WSB + 36*MB1);                 // (alias after fattn)
  float* cag = cah + (size_t)BB*TT*CAD;
  float* vtb = cag + (size_t)BB*TT*CAD;
  float* vsm = vtb + (size_t)BB*TT;
  float* ao  = (float*)(WSB + 40*MB1);                 // 40..56: attn_out (later mlp raw)
  float* x1b = (float*)(WSB + 56*MB1);                 // 56..72: x1 fp32 (early: y pair)
  unsigned short* yh = (unsigned short*)x1b;
  unsigned short* yl = yh + M4;
  float* hb  = (float*)(WSB + 72*MB1);                 // 72..136: h fp32 (conv input)
  float* h2  = (float*)(WSB + 136*MB1);                // 136..200: h bf16 pair (early: qkvo weight pairs, late: ca2)
  unsigned short* hh = (unsigned short*)h2;
  unsigned short* hl = hh + 4*M4;
  unsigned short* wqp = (unsigned short*)(WSB + 136*MB1);
  unsigned short* wkp = (unsigned short*)(WSB + 140*MB1);
  unsigned short* wvp = (unsigned short*)(WSB + 141*MB1);
  unsigned short* wop = (unsigned short*)(WSB + 142*MB1);
  float* ca2 = h2;
  unsigned short* ffip = (unsigned short*)(WSB + 200*MB1); // 200..216: ffn_in pair
  unsigned short* ffop = (unsigned short*)(WSB + 216*MB1); // 216..232: ffn_out pair

  const int BT = BB*TT;                     // 4096
  const int WQN = NH*HD*CC;                 // 1,048,576
  const int WKN = NKV*HD*CC;                // 262,144

  split_k<<<WQN/1024, 256, 0, stream>>>(w_q, wqp, wqp + WQN, WQN/4);
  split_k<<<WKN/1024, 256, 0, stream>>>(w_k, wkp, wkp + WKN, WKN/4);
  split_k<<<WKN/1024, 256, 0, stream>>>(w_v, wvp, wvp + WKN, WKN/4);
  split_k<<<WQN/1024, 256, 0, stream>>>(w_o, wop, wop + WQN, WQN/4);
  split_k<<<M4/1024, 256, 0, stream>>>(ffin, ffip, ffip + M4, (int)(M4/4));
  split_k<<<M4/1024, 256, 0, stream>>>(ffout, ffop, ffop + M4, (int)(M4/4));

  rmsnorm_pair_k<<<BT, 256, 0, stream>>>(x, xnh, xnl);
  gemm3_k<0><<<dim3(8, 32), 256, 0, stream>>>(xnh, xnl, wqp, wqp + WQN, qb, BT, 1024, 1024);
  gemm3_k<0><<<dim3(2, 32), 256, 0, stream>>>(xnh, xnl, wkp, wkp + WKN, kb, BT, 256, 1024);
  gemm3_k<0><<<dim3(2, 32), 256, 0, stream>>>(xnh, xnl, wvp, wvp + WKN, vb, BT, 256, 1024);
  rope_rms_k<<<BT*NH, 64, 0, stream>>>(qb, cs, sn, NH);
  rope_rms_k<<<BT*NKV, 64, 0, stream>>>(kb, cs, sn, NKV);
  gatev_k<<<BT, 256, 0, stream>>>(vb, xnh, xnl, ve, w_vg);
  fattn_k<<<dim3(TT/TQ, NH, BB), 256, 0, stream>>>(qb, kb, vb, pa, rfw, ralp, yh, yl);
  gemm3_k<0><<<dim3(8, 32), 256, 0, stream>>>(yh, yl, wop, wop + WQN, ao, BT, 1024, 1024);
  split_k<<<WQN/1024, 256, 0, stream>>>(ffgt, ffgp, ffgp + WQN, WQN/4);
  cain_k<<<BT, 256, 0, stream>>>(x, capi, cah);
  caconv_k<<<BT*CAD/256, 256, 0, stream>>>(cah, cacw, cag);
  caout_k<<<BT, 256, 0, stream>>>(cag, capo, ca1);
  x1_k<<<BT*CC/256, 256, 0, stream>>>(x, ao, ca1, x1b);
  rmsnorm_pair_k<<<BT, 256, 0, stream>>>(x1b, xnh, xnl);      // xm pair
  gemm3_k<1><<<dim3(32, 32), 256, 0, stream>>>(xnh, xnl, ffip, ffip + M4, hb, BT, FFNH, 1024);
  ffnconv4_k<<<dim3(FFNH/256, TT/64, BB), 256, 0, stream>>>(hb, ffcw, hh, hl);
  gemm3_k<0><<<dim3(8, 32), 256, 0, stream>>>(xnh, xnl, ffgp, ffgp + WQN, qb, BT, 1024, 1024);
  gemm3_k<0><<<dim3(8, 32), 256, 0, stream>>>(hh, hl, ffop, ffop + M4, ao, BT, 1024, FFNH);
  cain_k<<<BT, 256, 0, stream>>>(x1b, capi, cah);
  caconv_k<<<BT*CAD/256, 256, 0, stream>>>(cah, cacw, cag);
  caout_k<<<BT, 256, 0, stream>>>(cag, capo, ca2);
  vit_k<<<BT, 256, 0, stream>>>(x1b, vw1, vw2, vtb);
  vitsm_k<<<BT/256, 256, 0, stream>>>(vtb, vsm);
  final_k<<<BT*CC/256, 256, 0, stream>>>(x1b, ao, qb, ca2, vsm, (float*)d_out);
}

// Round 6
// 1441.298 us; speedup vs baseline: 1.9242x; 1.0918x over previous
//
#include <hip/hip_runtime.h>

// ---- constants ----
#define BB 4
#define TT 1024
#define CC 1024
#define NH 16
#define NKV 4
#define HD 64
#define FFNH 4096
#define CAD 32
#define TQ 64
#define TK 64

typedef short bf16x8 __attribute__((ext_vector_type(8)));
typedef float f32x4  __attribute__((ext_vector_type(4)));

#define AS1 __attribute__((address_space(1)))
#define AS3 __attribute__((address_space(3)))

__device__ __forceinline__ float sigf(float x){ return 1.f/(1.f+__expf(-x)); }
__device__ __forceinline__ float geluf(float x){ return 0.5f*x*(1.f+erff(x*0.70710678118654752f)); }

// fp32 -> bf16 (round-to-nearest-even), and back
__device__ __forceinline__ unsigned short f2bf(float f){
  unsigned int u = __float_as_uint(f);
  u += 0x7fffu + ((u >> 16) & 1u);
  return (unsigned short)(u >> 16);
}
__device__ __forceinline__ float bf2f(unsigned short h){
  return __uint_as_float(((unsigned int)h) << 16);
}

// ---- rmsnorm over last dim (1024), emitting bf16 hi/lo pair ----
__global__ __launch_bounds__(256) void rmsnorm_pair_k(const float* __restrict__ x,
    unsigned short* __restrict__ oh, unsigned short* __restrict__ ol){
  int row = blockIdx.x;
  const float* xr = x + (size_t)row * CC;
  float v[4]; float ss = 0.f;
  #pragma unroll
  for (int i = 0; i < 4; i++){ v[i] = xr[threadIdx.x + 256*i]; ss += v[i]*v[i]; }
  #pragma unroll
  for (int off = 1; off < 64; off <<= 1) ss += __shfl_xor(ss, off);
  __shared__ float red[4];
  if ((threadIdx.x & 63) == 0) red[threadIdx.x >> 6] = ss;
  __syncthreads();
  float tot = red[0]+red[1]+red[2]+red[3];
  float rs = rsqrtf(tot * (1.f/CC) + 1e-6f);
  size_t base = (size_t)row * CC;
  #pragma unroll
  for (int i = 0; i < 4; i++){
    float r = v[i]*rs;
    unsigned short h = f2bf(r);
    oh[base + threadIdx.x + 256*i] = h;
    ol[base + threadIdx.x + 256*i] = f2bf(r - bf2f(h));
  }
}

// ---- generic fp32 -> bf16 hi/lo splitter (for weights) ----
__global__ __launch_bounds__(256) void split_k(const float* __restrict__ in,
    unsigned short* __restrict__ hi, unsigned short* __restrict__ lo, int n4){
  int i = blockIdx.x*256 + threadIdx.x;
  if (i >= n4) return;
  float4 v = ((const float4*)in)[i];
  unsigned short h0 = f2bf(v.x), h1 = f2bf(v.y), h2v = f2bf(v.z), h3 = f2bf(v.w);
  ushort4 hv = { h0, h1, h2v, h3 };
  ushort4 lv = { f2bf(v.x - bf2f(h0)), f2bf(v.y - bf2f(h1)),
                 f2bf(v.z - bf2f(h2v)), f2bf(v.w - bf2f(h3)) };
  ((ushort4*)hi)[i] = hv;
  ((ushort4*)lo)[i] = lv;
}

// ---- bf16x3 MFMA GEMM, optional split-K via blockIdx.z.
//      Each z-chunk covers KC of K and writes partial C at C + z*M*N.
//      Call with gridDim.z == K/KC; KC % 32 == 0. EPI applied only when no split. ----
template<int EPI>
__global__ __launch_bounds__(256) void gemm3_k(
    const unsigned short* __restrict__ Ah, const unsigned short* __restrict__ Al,
    const unsigned short* __restrict__ Wh, const unsigned short* __restrict__ Wl,
    float* __restrict__ C, int M, int N, int K, int KC)
{
  __shared__ unsigned short AhS[128*32];
  __shared__ unsigned short AlS[128*32];
  __shared__ unsigned short WhS[128*32];
  __shared__ unsigned short WlS[128*32];
  int tid  = threadIdx.x;
  int lane = tid & 63, wave = tid >> 6;
  int wr = wave >> 1, wc = wave & 1;
  int m0 = blockIdx.y << 7, n0 = blockIdx.x << 7;
  int z  = blockIdx.z;
  int kbase = z * KC;
  float* Cz = C + (size_t)z * M * N;
  int lr = lane & 15, lc = lane >> 4;

  int offA[4], offB[4];
  #pragma unroll
  for (int m = 0; m < 4; m++){
    int row = wr*64 + m*16 + lr;
    offA[m] = row*64 + ((lc ^ ((row >> 1) & 3)) << 4);
  }
  #pragma unroll
  for (int n = 0; n < 4; n++){
    int row = wc*64 + n*16 + lr;
    offB[n] = row*64 + ((lc ^ ((row >> 1) & 3)) << 4);
  }

  f32x4 acc[4][4] = {};

  for (int k0 = kbase; k0 < kbase + KC; k0 += 32){
    __syncthreads();
    {
      const unsigned short* srcs[4] = { Ah, Al, Wh, Wl };
      unsigned short* dsts[4] = { AhS, AlS, WhS, WlS };
      int rb[4] = { m0, m0, n0, n0 };
      #pragma unroll
      for (int tle = 0; tle < 4; tle++){
        #pragma unroll
        for (int i = 0; i < 2; i++){
          int s = i*256 + tid;
          int row = s >> 2;
          int c = (s & 3) ^ ((row >> 1) & 3);
          const unsigned short* gp = srcs[tle] + (size_t)(rb[tle] + row)*K + (k0 + c*8);
          unsigned short* lp = dsts[tle] + i*2048 + wave*512;
          __builtin_amdgcn_global_load_lds((const AS1 void*)gp, (AS3 void*)lp, 16, 0, 0);
        }
      }
    }
    __syncthreads();

    bf16x8 ah[4], al[4], bh[4], bl[4];
    #pragma unroll
    for (int m = 0; m < 4; m++){
      ah[m] = *(const bf16x8*)((const char*)AhS + offA[m]);
      al[m] = *(const bf16x8*)((const char*)AlS + offA[m]);
    }
    #pragma unroll
    for (int n = 0; n < 4; n++){
      bh[n] = *(const bf16x8*)((const char*)WhS + offB[n]);
      bl[n] = *(const bf16x8*)((const char*)WlS + offB[n]);
    }
    #pragma unroll
    for (int m = 0; m < 4; m++){
      #pragma unroll
      for (int n = 0; n < 4; n++){
        acc[m][n] = __builtin_amdgcn_mfma_f32_16x16x32_bf16(al[m], bh[n], acc[m][n], 0, 0, 0);
        acc[m][n] = __builtin_amdgcn_mfma_f32_16x16x32_bf16(ah[m], bl[n], acc[m][n], 0, 0, 0);
        acc[m][n] = __builtin_amdgcn_mfma_f32_16x16x32_bf16(ah[m], bh[n], acc[m][n], 0, 0, 0);
      }
    }
  }

  #pragma unroll
  for (int m = 0; m < 4; m++){
    int r0 = m0 + wr*64 + m*16 + lc*4;
    #pragma unroll
    for (int n = 0; n < 4; n++){
      int col = n0 + wc*64 + n*16 + lr;
      #pragma unroll
      for (int r = 0; r < 4; r++){
        float z2 = acc[m][n][r];
        if (EPI == 1){ z2 = fmaxf(z2, 0.f); z2 = z2*z2; }
        Cz[(size_t)(r0 + r)*N + col] = z2;
      }
    }
  }
}

// ---- sum split-K partials: out[i] = sum_z parts[z*n + i] ----
__global__ __launch_bounds__(256) void redsum_k(const float* __restrict__ p,
    float* __restrict__ o, size_t n, int parts){
  size_t i = ((size_t)blockIdx.x*256 + threadIdx.x)*4;
  float4 s = *(const float4*)(p + i);
  for (int z = 1; z < parts; z++){
    float4 q = *(const float4*)(p + (size_t)z*n + i);
    s.x += q.x; s.y += q.y; s.z += q.z; s.w += q.w;
  }
  *(float4*)(o + i) = s;
}

// ---- rope + head-rmsnorm * 1.2 ----
__global__ __launch_bounds__(64) void rope_rms_k(float* __restrict__ q,
    const float* __restrict__ cs, const float* __restrict__ sn, int nh){
  int idx = blockIdx.x;
  int t = (idx / nh) & (TT-1);
  float* qp = q + (size_t)idx * HD;
  int d = threadIdx.x;
  int dl = d & 31;
  float c = cs[t*32 + dl], s = sn[t*32 + dl];
  float v0 = qp[d];
  float vp = qp[(d < 32) ? d + 32 : d - 32];
  float r = (d < 32) ? (v0*c + vp*s) : (v0*c - vp*s);
  float ss = r*r;
  #pragma unroll
  for (int off = 1; off < 64; off <<= 1) ss += __shfl_xor(ss, off);
  float rs = rsqrtf(ss*(1.f/HD) + 1e-6f) * 1.2f;
  qp[d] = r*rs;
}

// ---- v += 3*sigmoid(xn[:,:12] @ wg^T) * ve ----
__global__ __launch_bounds__(256) void gatev_k(float* __restrict__ v,
    const unsigned short* __restrict__ xnh, const unsigned short* __restrict__ xnl,
    const float* __restrict__ ve, const float* __restrict__ wg){
  int bt = blockIdx.x;
  int tid = threadIdx.x;
  int kv = tid >> 6;
  float s = 0.f;
  #pragma unroll
  for (int j = 0; j < 12; j++){
    float xv = bf2f(xnh[(size_t)bt*CC + j]) + bf2f(xnl[(size_t)bt*CC + j]);
    s += xv*wg[kv*12+j];
  }
  float gate = 3.f * sigf(s);
  size_t i = (size_t)bt*(NKV*HD) + tid;
  v[i] += gate * ve[i];
}

// ---- MFMA flash attention (S^T trick), occupancy-tuned (verified round 5) ----
__global__ __launch_bounds__(256) void fattn_k(
    const float* __restrict__ q, const float* __restrict__ k, const float* __restrict__ v,
    const float* __restrict__ pa, const float* __restrict__ rw,
    const float* __restrict__ alphap,
    unsigned short* __restrict__ yh, unsigned short* __restrict__ yl)
{
  int qt = blockIdx.x;
  int h  = blockIdx.y;
  int b  = blockIdx.z;
  int kv = h >> 2;
  int t0 = qt * TQ;
  int tid = threadIdx.x;
  int lane = tid & 63, w = tid >> 6;
  int dl = lane & 15, gq = lane >> 4;

  __shared__ __align__(16) unsigned short Kh[4096], Kl[4096];   // [64 k][64 d] swz, bf16 pair
  __shared__ __align__(16) unsigned short Vh[64][68];           // [k][d] bf16 hi
  __shared__ __align__(16) unsigned short SBs[66*68];           // pa tile bf16
  __shared__ __align__(16) unsigned short Ph[4][1024];          // per-wave P [16 q][64 k] swz, hi

  // Q fragments direct from global (lane's q row = 16w+dl)
  bf16x8 qfh[2], qfl[2];
  {
    const float* qrow = q + (((size_t)(b*TT + t0 + 16*w + dl))*NH + h)*HD;
    #pragma unroll
    for (int ks = 0; ks < 2; ks++){
      float4 a = *(const float4*)(qrow + (gq+4*ks)*8);
      float4 bq = *(const float4*)(qrow + (gq+4*ks)*8 + 4);
      float vv[8] = {a.x,a.y,a.z,a.w,bq.x,bq.y,bq.z,bq.w};
      #pragma unroll
      for (int i = 0; i < 8; i++){
        unsigned short hv = f2bf(vv[i]);
        qfh[ks][i] = (short)hv;
        qfl[ks][i] = (short)f2bf(vv[i] - bf2f(hv));
      }
    }
  }

  float alpha = *alphap;
  float w9[9];
  #pragma unroll
  for (int j = 0; j < 9; j++) w9[j] = rw[h*9+j]*alpha;

  float m_i = -1e30f, l_i = 0.f;
  f32x4 acc_o[4] = {};
  int ql = 16*w + dl;

  for (int kt = 0; kt <= qt; kt++){
    int k0 = kt*TK;
    __syncthreads();
    #pragma unroll
    for (int it = 0; it < 4; it++){
      int s = it*256 + tid;
      int r = s >> 4, d4 = (s & 15) << 2;
      const float* kp = k + (((size_t)(b*TT + k0 + r))*NKV + kv)*HD + d4;
      float4 val = *(const float4*)kp;
      ushort4 hv = { f2bf(val.x), f2bf(val.y), f2bf(val.z), f2bf(val.w) };
      ushort4 lv = { f2bf(val.x - bf2f(hv.x)), f2bf(val.y - bf2f(hv.y)),
                     f2bf(val.z - bf2f(hv.z)), f2bf(val.w - bf2f(hv.w)) };
      int idx = r*64 + (((d4 >> 3) ^ (r & 7)) << 3) + (d4 & 7);
      *(ushort4*)&Kh[idx] = hv;
      *(ushort4*)&Kl[idx] = lv;
      const float* vp = v + (((size_t)(b*TT + k0 + r))*NKV + kv)*HD + d4;
      float4 vval = *(const float4*)vp;
      ushort4 vh4 = { f2bf(vval.x), f2bf(vval.y), f2bf(vval.z), f2bf(vval.w) };
      *(ushort4*)&Vh[r][d4] = vh4;
    }
    #pragma unroll
    for (int it = 0; it < 4; it++){
      int e = it*256 + tid;
      int r = e >> 4, c4 = (e & 15) << 2;
      const float* pp = pa + ((size_t)(b*NH + h)*TT + (t0 + r))*TT + (k0 + c4);
      float4 pv = *(const float4*)pp;
      unsigned short* sp = &SBs[(r+1)*68 + (c4+1)];
      sp[0] = f2bf(pv.x); sp[1] = f2bf(pv.y); sp[2] = f2bf(pv.z); sp[3] = f2bf(pv.w);
    }
    for (int e = tid; e < 260; e += 256){
      int li, lj;
      if (e < 132){ li = (e < 66) ? 0 : 65; lj = (e < 66) ? e : e - 66; }
      else { int idx = e - 132; li = 1 + (idx & 63); lj = (idx >> 6) ? 65 : 0; }
      int gr = t0 - 1 + li, gc = k0 - 1 + lj;
      float pv = 0.f;
      if (gr >= 0 && gr < TT && gc >= 0 && gc < TT)
        pv = pa[((size_t)(b*NH + h)*TT + gr)*TT + gc];
      SBs[li*68 + lj] = f2bf(pv);
    }
    __syncthreads();

    f32x4 acc_s[4] = {};
    __builtin_amdgcn_s_setprio(1);
    #pragma unroll
    for (int ks = 0; ks < 2; ks++){
      #pragma unroll
      for (int kf = 0; kf < 4; kf++){
        int row = 16*kf + dl;
        int idx = row*64 + (((gq + 4*ks) ^ (row & 7)) << 3);
        bf16x8 kh_ = *(const bf16x8*)&Kh[idx];
        bf16x8 kl_ = *(const bf16x8*)&Kl[idx];
        acc_s[kf] = __builtin_amdgcn_mfma_f32_16x16x32_bf16(kl_, qfh[ks], acc_s[kf], 0, 0, 0);
        acc_s[kf] = __builtin_amdgcn_mfma_f32_16x16x32_bf16(kh_, qfl[ks], acc_s[kf], 0, 0, 0);
        acc_s[kf] = __builtin_amdgcn_mfma_f32_16x16x32_bf16(kh_, qfh[ks], acc_s[kf], 0, 0, 0);
      }
    }
    __builtin_amdgcn_s_setprio(0);

    #pragma unroll
    for (int kf = 0; kf < 4; kf++){
      int kb = 16*kf + 4*gq;
      float cv0=0.f, cv1=0.f, cv2=0.f, cv3=0.f;
      #pragma unroll
      for (int dy = 0; dy < 3; dy++){
        const unsigned short* rp = &SBs[(ql + dy)*68 + kb];
        float u0 = bf2f(rp[0]), u1 = bf2f(rp[1]), u2 = bf2f(rp[2]),
              u3 = bf2f(rp[3]), u4 = bf2f(rp[4]), u5 = bf2f(rp[5]);
        float wa = w9[dy*3+0], wb = w9[dy*3+1], wcq = w9[dy*3+2];
        cv0 += u0*wa + u1*wb + u2*wcq;
        cv1 += u1*wa + u2*wb + u3*wcq;
        cv2 += u2*wa + u3*wb + u4*wcq;
        cv3 += u3*wa + u4*wb + u5*wcq;
      }
      int grow = t0 + ql;
      float s0 = acc_s[kf][0]*0.125f + cv0; if (k0 + kb + 0 > grow) s0 = -1e30f;
      float s1 = acc_s[kf][1]*0.125f + cv1; if (k0 + kb + 1 > grow) s1 = -1e30f;
      float s2 = acc_s[kf][2]*0.125f + cv2; if (k0 + kb + 2 > grow) s2 = -1e30f;
      float s3 = acc_s[kf][3]*0.125f + cv3; if (k0 + kb + 3 > grow) s3 = -1e30f;
      acc_s[kf][0] = s0; acc_s[kf][1] = s1; acc_s[kf][2] = s2; acc_s[kf][3] = s3;
    }

    float rm = -1e30f;
    #pragma unroll
    for (int kf = 0; kf < 4; kf++){
      rm = fmaxf(rm, fmaxf(fmaxf(acc_s[kf][0], acc_s[kf][1]),
                           fmaxf(acc_s[kf][2], acc_s[kf][3])));
    }
    rm = fmaxf(rm, __shfl_xor(rm, 16));
    rm = fmaxf(rm, __shfl_xor(rm, 32));
    float mn = fmaxf(m_i, rm);
    float sc = __expf(m_i - mn);
    m_i = mn;
    float rs = 0.f;
    #pragma unroll
    for (int kf = 0; kf < 4; kf++){
      float p0 = __expf(acc_s[kf][0] - mn);
      float p1 = __expf(acc_s[kf][1] - mn);
      float p2 = __expf(acc_s[kf][2] - mn);
      float p3 = __expf(acc_s[kf][3] - mn);
      rs += p0 + p1 + p2 + p3;
      ushort4 hv = { f2bf(p0), f2bf(p1), f2bf(p2), f2bf(p3) };
      int kbl = 16*kf + 4*gq;
      int idx = dl*64 + ((((kbl >> 3)) ^ (dl & 7)) << 3) + (kbl & 7);
      *(ushort4*)&Ph[w][idx] = hv;
    }
    rs += __shfl_xor(rs, 16);
    rs += __shfl_xor(rs, 32);
    l_i = l_i*sc + rs;

    float scR0 = __shfl(sc, gq*4 + 0);
    float scR1 = __shfl(sc, gq*4 + 1);
    float scR2 = __shfl(sc, gq*4 + 2);
    float scR3 = __shfl(sc, gq*4 + 3);
    #pragma unroll
    for (int nf = 0; nf < 4; nf++){
      acc_o[nf][0] *= scR0; acc_o[nf][1] *= scR1;
      acc_o[nf][2] *= scR2; acc_o[nf][3] *= scR3;
    }

    #pragma unroll
    for (int ks = 0; ks < 2; ks++){
      int idxp = dl*64 + (((gq + 4*ks) ^ (dl & 7)) << 3);
      bf16x8 pfh = *(const bf16x8*)&Ph[w][idxp];
      __builtin_amdgcn_s_setprio(1);
      #pragma unroll
      for (int nf = 0; nf < 4; nf++){
        bf16x8 vh_;
        #pragma unroll
        for (int i = 0; i < 8; i++)
          vh_[i] = (short)Vh[ks*32 + gq*8 + i][16*nf + dl];
        acc_o[nf] = __builtin_amdgcn_mfma_f32_16x16x32_bf16(pfh, vh_, acc_o[nf], 0, 0, 0);
      }
      __builtin_amdgcn_s_setprio(0);
    }
  }

  float li0 = __shfl(l_i, gq*4 + 0);
  float li1 = __shfl(l_i, gq*4 + 1);
  float li2 = __shfl(l_i, gq*4 + 2);
  float li3 = __shfl(l_i, gq*4 + 3);
  float inv0 = 1.f/li0, inv1 = 1.f/li1, inv2 = 1.f/li2, inv3 = 1.f/li3;
  #pragma unroll
  for (int nf = 0; nf < 4; nf++){
    int dcol = 16*nf + dl;
    #pragma unroll
    for (int reg = 0; reg < 4; reg++){
      float invv = (reg == 0) ? inv0 : (reg == 1) ? inv1 : (reg == 2) ? inv2 : inv3;
      float val = acc_o[nf][reg] * invv;
      size_t bix = (((size_t)(b*TT + t0 + 16*w + gq*4 + reg))*NH + h)*HD + dcol;
      unsigned short hv = f2bf(val);
      yh[bix] = hv;
      yl[bix] = f2bf(val - bf2f(hv));
    }
  }
}

// ---- CA: in-projection (K=1024 -> 32) ----
__global__ __launch_bounds__(256) void cain_k(const float* __restrict__ x,
    const float* __restrict__ pi, float* __restrict__ out){
  int bt = blockIdx.x;
  __shared__ float xs[CC];
  __shared__ float pr[8][33];
  for (int i = threadIdx.x; i < CC; i += 256) xs[i] = x[(size_t)bt*CC + i];
  __syncthreads();
  int d = threadIdx.x & 31, sl = threadIdx.x >> 5;
  const float* pip = pi + (size_t)d*CC + sl*128;
  float s = 0.f;
  #pragma unroll 8
  for (int i = 0; i < 128; i++) s += xs[sl*128+i]*pip[i];
  pr[sl][d] = s;
  __syncthreads();
  if (threadIdx.x < 32){
    float tot = 0.f;
    #pragma unroll
    for (int j = 0; j < 8; j++) tot += pr[j][threadIdx.x];
    out[(size_t)bt*CAD + threadIdx.x] = tot;
  }
}

// ---- CA: depthwise conv over T + exact gelu ----
__global__ __launch_bounds__(256) void caconv_k(const float* __restrict__ hin,
    const float* __restrict__ cw, float* __restrict__ gout){
  int i = blockIdx.x*256 + threadIdx.x;
  int d = i & 31;
  int bt = i >> 5;
  int t = bt & (TT-1);
  float cc = hin[i];
  float hm = (t > 0)      ? hin[i-32] : 0.f;
  float hp = (t < TT-1)   ? hin[i+32] : 0.f;
  float hc = cc + 0.1f*(hm*cw[d*3] + cc*cw[d*3+1] + hp*cw[d*3+2]);
  gout[i] = geluf(hc);
}

// ---- CA: out-projection (K=32 -> 1024) ----
__global__ __launch_bounds__(256) void caout_k(const float* __restrict__ g,
    const float* __restrict__ po, float* __restrict__ out){
  int bt = blockIdx.x;
  __shared__ float gs[CAD];
  if (threadIdx.x < CAD) gs[threadIdx.x] = g[(size_t)bt*CAD + threadIdx.x];
  __syncthreads();
  for (int c = threadIdx.x; c < CC; c += 256){
    const float* pp = po + (size_t)c*CAD;
    float s = 0.f;
    #pragma unroll
    for (int d2 = 0; d2 < CAD; d2++) s += gs[d2]*pp[d2];
    out[(size_t)bt*CC + c] = s;
  }
}

// ---- x1 = x + attn_out * (1 + 0.1*tanh(ca1)) ----
__global__ __launch_bounds__(256) void x1_k(const float* __restrict__ x,
    const float* __restrict__ ao, const float* __restrict__ ca1, float* __restrict__ x1){
  size_t i = (size_t)blockIdx.x*256 + threadIdx.x;
  x1[i] = x[i] + ao[i] * (1.f + 0.1f*tanhf(ca1[i]));
}

// ---- fused 4-pass FFN depthwise conv (register cascade), bf16 pair out ----
__global__ __launch_bounds__(256) void ffnconv4_k(const float* __restrict__ hin,
    const float* __restrict__ cw, unsigned short* __restrict__ hh, unsigned short* __restrict__ hl){
  int c  = blockIdx.x*256 + threadIdx.x;
  int ta = blockIdx.y*64;
  int b  = blockIdx.z;
  float w0 = cw[c*3+0], w1 = cw[c*3+1], w2 = cw[c*3+2];
  size_t base = (size_t)b*TT*FFNH + c;
  float i0=0.f,i1=0.f,i2=0.f;
  float a0=0.f,a1=0.f,a2=0.f;
  float b0=0.f,b1=0.f,b2=0.f;
  float c0=0.f,c1=0.f,c2=0.f;
  for (int t = ta-4; t <= ta+67; t++){
    float iv = 0.f;
    if (t >= 0 && t < TT) iv = hin[base + (size_t)t*FFNH];
    i0 = i1; i1 = i2; i2 = iv;
    float s1 = i1 + 0.1f*(i0*w0 + i1*w1 + i2*w2);
    if (t-1 < 0 || t-1 >= TT) s1 = 0.f;
    a0 = a1; a1 = a2; a2 = s1;
    float s2 = a1 + 0.1f*(a0*w0 + a1*w1 + a2*w2);
    if (t-2 < 0 || t-2 >= TT) s2 = 0.f;
    b0 = b1; b1 = b2; b2 = s2;
    float s3 = b1 + 0.1f*(b0*w0 + b1*w1 + b2*w2);
    if (t-3 < 0 || t-3 >= TT) s3 = 0.f;
    c0 = c1; c1 = c2; c2 = s3;
    float s4 = c1 + 0.1f*(c0*w0 + c1*w1 + c2*w2);
    int t4 = t-4;
    if (t4 >= ta){
      size_t oix = base + (size_t)t4*FFNH;
      unsigned short hv = f2bf(s4);
      hh[oix] = hv;
      hl[oix] = f2bf(s4 - bf2f(hv));
    }
  }
}

// ---- vit scalar gate ----
__global__ __launch_bounds__(256) void vit_k(const float* __restrict__ x1,
    const float* __restrict__ w1, const float* __restrict__ w2,
    float* __restrict__ vout){
  int bt = blockIdx.x;
  __shared__ float xs[CC];
  __shared__ float pr[8][33];
  __shared__ float g32[32];
  for (int i = threadIdx.x; i < CC; i += 256) xs[i] = x1[(size_t)bt*CC + i];
  __syncthreads();
  int d = threadIdx.x & 31, sl = threadIdx.x >> 5;
  const float* wp = w1 + (size_t)d*CC + sl*128;
  float s = 0.f;
  #pragma unroll 8
  for (int i = 0; i < 128; i++) s += xs[sl*128+i]*wp[i];
  pr[sl][d] = s;
  __syncthreads();
  if (threadIdx.x < 32){
    float tot = 0.f;
    #pragma unroll
    for (int j = 0; j < 8; j++) tot += pr[j][threadIdx.x];
    g32[threadIdx.x] = geluf(tot);
  }
  __syncthreads();
  if (threadIdx.x == 0){
    float s2 = 0.f;
    #pragma unroll
    for (int d2 = 0; d2 < 32; d2++) s2 += g32[d2]*w2[d2];
    vout[bt] = sigf(s2);
  }
}

// ---- vit smoothing + threshold ----
__global__ __launch_bounds__(256) void vitsm_k(const float* __restrict__ vin, float* __restrict__ vout){
  int i = blockIdx.x*256 + threadIdx.x;
  int t = i & (TT-1), b = i >> 10;
  float s = 0.f;
  #pragma unroll
  for (int dd = -2; dd <= 2; dd++){
    int tt = t + dd;
    if (tt >= 0 && tt < TT) s += vin[(b << 10) + tt];
  }
  s *= 0.2f;
  float vv = 0.7f*vin[i] + 0.3f*s;
  vout[i] = (vv > 0.3f) ? vv : 0.1f*vv;
}

// ---- final: out = x1 + mlp*sig(g)*(1+0.1*tanh(ca2)) * vit ----
__global__ __launch_bounds__(256) void final_k(const float* __restrict__ x1,
    const float* __restrict__ mlpraw, const float* __restrict__ g,
    const float* __restrict__ ca2, const float* __restrict__ vsm,
    float* __restrict__ out){
  size_t i = (size_t)blockIdx.x*256 + threadIdx.x;
  size_t bt = i >> 10;
  float mlp = mlpraw[i] * sigf(g[i]) * (1.f + 0.1f*tanhf(ca2[i]));
  out[i] = x1[i] + mlp * vsm[bt];
}

extern "C" void kernel_launch(void* const* d_in, const int* in_sizes, int n_in,
                              void* d_out, int out_size, void* d_ws, size_t ws_size,
                              hipStream_t stream) {
  (void)in_sizes; (void)n_in; (void)out_size; (void)ws_size;
  const float* x     = (const float*)d_in[0];
  const float* ve    = (const float*)d_in[1];
  const float* cs    = (const float*)d_in[2];
  const float* sn    = (const float*)d_in[3];
  const float* pa    = (const float*)d_in[4];
  const float* w_q   = (const float*)d_in[5];
  const float* w_k   = (const float*)d_in[6];
  const float* w_v   = (const float*)d_in[7];
  const float* w_o   = (const float*)d_in[8];
  const float* w_vg  = (const float*)d_in[9];
  const float* rfw   = (const float*)d_in[10];
  const float* ralp  = (const float*)d_in[11];
  const float* capi  = (const float*)d_in[12];
  const float* cacw  = (const float*)d_in[13];
  const float* capo  = (const float*)d_in[14];
  const float* ffin  = (const float*)d_in[15];
  const float* ffcw  = (const float*)d_in[16];
  const float* ffout = (const float*)d_in[17];
  const float* ffgt  = (const float*)d_in[18];
  const float* vw1   = (const float*)d_in[19];
  const float* vw2   = (const float*)d_in[20];

  // ---- workspace layout (lifetimes disjoint where aliased), 232 MiB total ----
  const size_t M4  = (size_t)BB*TT*CC;      // 4,194,304 elements
  const size_t MB1 = 1ull << 20;
  char* WSB = (char*)d_ws;

  unsigned short* xnh = (unsigned short*)WSB;          //  0..16MiB: xn/xm bf16 pair
  unsigned short* xnl = xnh + M4;
  float* ca1 = (float*)WSB;                            //  (alias, after xn consumed)
  float* qb  = (float*)(WSB + 16*MB1);                 // 16..32: q fp32 (later ffn gate)
  float* kb  = (float*)(WSB + 32*MB1);                 // 32..36: k fp32
  unsigned short* ffgp = (unsigned short*)(WSB + 32*MB1); // (alias after fattn: ffgt pair)
  float* vb  = (float*)(WSB + 36*MB1);                 // 36..40: v fp32
  float* cah = (float*)(WSB + 36*MB1);                 // (alias after fattn)
  float* cag = cah + (size_t)BB*TT*CAD;
  float* vtb = cag + (size_t)BB*TT*CAD;
  float* vsm = vtb + (size_t)BB*TT;
  float* ao  = (float*)(WSB + 40*MB1);                 // 40..56: attn_out (later mlp raw)
  float* x1b = (float*)(WSB + 56*MB1);                 // 56..72: x1 fp32 (early: y pair)
  unsigned short* yh = (unsigned short*)x1b;
  unsigned short* yl = yh + M4;
  float* hb  = (float*)(WSB + 72*MB1);                 // 72..136: h fp32 conv input; also split-K partial pool when free
  float* h2  = (float*)(WSB + 136*MB1);                // 136..200: h bf16 pair (early: qkvo weight pairs, late: ca2)
  unsigned short* hh = (unsigned short*)h2;
  unsigned short* hl = hh + 4*M4;
  unsigned short* wqp = (unsigned short*)(WSB + 136*MB1);
  unsigned short* wkp = (unsigned short*)(WSB + 140*MB1);
  unsigned short* wvp = (unsigned short*)(WSB + 141*MB1);
  unsigned short* wop = (unsigned short*)(WSB + 142*MB1);
  float* ca2 = h2;
  unsigned short* ffip = (unsigned short*)(WSB + 200*MB1); // 200..216: ffn_in pair
  unsigned short* ffop = (unsigned short*)(WSB + 216*MB1); // 216..232: ffn_out pair

  // split-K partial pool (all uses of hb as partials are between its live phases)
  float* kpart = hb;                                   // 4 x 4MB   (early)
  float* vpart = hb + 4*M4/4;                          // +16MiB: 4 x 4MB (early)
  float* qpart = hb + 8*M4/4;                          // +32MiB: 2 x 16MB (early)
  float* opart = hb;                                   // 2 x 16MB (after fattn)
  float* gpart = hb;                                   // 2 x 16MB (after ffnconv4)
  float* fpart = hb;                                   // 4 x 16MB (after gate reduce)

  const int BT = BB*TT;                     // 4096
  const int WQN = NH*HD*CC;                 // 1,048,576
  const int WKN = NKV*HD*CC;                // 262,144

  split_k<<<WQN/1024, 256, 0, stream>>>(w_q, wqp, wqp + WQN, WQN/4);
  split_k<<<WKN/1024, 256, 0, stream>>>(w_k, wkp, wkp + WKN, WKN/4);
  split_k<<<WKN/1024, 256, 0, stream>>>(w_v, wvp, wvp + WKN, WKN/4);
  split_k<<<WQN/1024, 256, 0, stream>>>(w_o, wop, wop + WQN, WQN/4);
  split_k<<<M4/1024, 256, 0, stream>>>(ffin, ffip, ffip + M4, (int)(M4/4));
  split_k<<<M4/1024, 256, 0, stream>>>(ffout, ffop, ffop + M4, (int)(M4/4));

  rmsnorm_pair_k<<<BT, 256, 0, stream>>>(x, xnh, xnl);
  // q: split-K=2 (256 -> 512 blocks)
  gemm3_k<0><<<dim3(8, 32, 2), 256, 0, stream>>>(xnh, xnl, wqp, wqp + WQN, qpart, BT, 1024, 1024, 512);
  redsum_k<<<4096, 256, 0, stream>>>(qpart, qb, (size_t)BT*1024, 2);
  // k, v: split-K=4 (64 -> 256 blocks)
  gemm3_k<0><<<dim3(2, 32, 4), 256, 0, stream>>>(xnh, xnl, wkp, wkp + WKN, kpart, BT, 256, 1024, 256);
  redsum_k<<<1024, 256, 0, stream>>>(kpart, kb, (size_t)BT*256, 4);
  gemm3_k<0><<<dim3(2, 32, 4), 256, 0, stream>>>(xnh, xnl, wvp, wvp + WKN, vpart, BT, 256, 1024, 256);
  redsum_k<<<1024, 256, 0, stream>>>(vpart, vb, (size_t)BT*256, 4);
  rope_rms_k<<<BT*NH, 64, 0, stream>>>(qb, cs, sn, NH);
  rope_rms_k<<<BT*NKV, 64, 0, stream>>>(kb, cs, sn, NKV);
  gatev_k<<<BT, 256, 0, stream>>>(vb, xnh, xnl, ve, w_vg);
  fattn_k<<<dim3(TT/TQ, NH, BB), 256, 0, stream>>>(qb, kb, vb, pa, rfw, ralp, yh, yl);
  // o: split-K=2
  gemm3_k<0><<<dim3(8, 32, 2), 256, 0, stream>>>(yh, yl, wop, wop + WQN, opart, BT, 1024, 1024, 512);
  redsum_k<<<4096, 256, 0, stream>>>(opart, ao, (size_t)BT*1024, 2);
  split_k<<<WQN/1024, 256, 0, stream>>>(ffgt, ffgp, ffgp + WQN, WQN/4);
  cain_k<<<BT, 256, 0, stream>>>(x, capi, cah);
  caconv_k<<<BT*CAD/256, 256, 0, stream>>>(cah, cacw, cag);
  caout_k<<<BT, 256, 0, stream>>>(cag, capo, ca1);
  x1_k<<<BT*CC/256, 256, 0, stream>>>(x, ao, ca1, x1b);
  rmsnorm_pair_k<<<BT, 256, 0, stream>>>(x1b, xnh, xnl);      // xm pair
  gemm3_k<1><<<dim3(32, 32), 256, 0, stream>>>(xnh, xnl, ffip, ffip + M4, hb, BT, FFNH, 1024, 1024);
  ffnconv4_k<<<dim3(FFNH/256, TT/64, BB), 256, 0, stream>>>(hb, ffcw, hh, hl);
  // gate: split-K=2 (hb free after ffnconv4)
  gemm3_k<0><<<dim3(8, 32, 2), 256, 0, stream>>>(xnh, xnl, ffgp, ffgp + WQN, gpart, BT, 1024, 1024, 512);
  redsum_k<<<4096, 256, 0, stream>>>(gpart, qb, (size_t)BT*1024, 2);
  // ffn_out: split-K=4 (256 -> 1024 blocks)
  gemm3_k<0><<<dim3(8, 32, 4), 256, 0, stream>>>(hh, hl, ffop, ffop + M4, fpart, BT, 1024, 4096, 1024);
  redsum_k<<<4096, 256, 0, stream>>>(fpart, ao, (size_t)BT*1024, 4);
  cain_k<<<BT, 256, 0, stream>>>(x1b, capi, cah);
  caconv_k<<<BT*CAD/256, 256, 0, stream>>>(cah, cacw, cag);
  caout_k<<<BT, 256, 0, stream>>>(cag, capo, ca2);
  vit_k<<<BT, 256, 0, stream>>>(x1b, vw1, vw2, vtb);
  vitsm_k<<<BT/256, 256, 0, stream>>>(vtb, vsm);
  final_k<<<BT*CC/256, 256, 0, stream>>>(x1b, ao, qb, ca2, vsm, (float*)d_out);
}

// Round 7
// 1403.913 us; speedup vs baseline: 1.9754x; 1.0266x over previous
//
#include <hip/hip_runtime.h>

// ---- constants ----
#define BB 4
#define TT 1024
#define CC 1024
#define NH 16
#define NKV 4
#define HD 64
#define FFNH 4096
#define CAD 32
#define TQ 64
#define TK 64

typedef short bf16x8 __attribute__((ext_vector_type(8)));
typedef float f32x4  __attribute__((ext_vector_type(4)));

#define AS1 __attribute__((address_space(1)))
#define AS3 __attribute__((address_space(3)))

__device__ __forceinline__ float sigf(float x){ return 1.f/(1.f+__expf(-x)); }
__device__ __forceinline__ float geluf(float x){ return 0.5f*x*(1.f+erff(x*0.70710678118654752f)); }

__device__ __forceinline__ unsigned short f2bf(float f){
  unsigned int u = __float_as_uint(f);
  u += 0x7fffu + ((u >> 16) & 1u);
  return (unsigned short)(u >> 16);
}
__device__ __forceinline__ float bf2f(unsigned short h){
  return __uint_as_float(((unsigned int)h) << 16);
}

// ---- rmsnorm over last dim (1024), emitting bf16 hi/lo pair ----
__global__ __launch_bounds__(256) void rmsnorm_pair_k(const float* __restrict__ x,
    unsigned short* __restrict__ oh, unsigned short* __restrict__ ol){
  int row = blockIdx.x;
  const float* xr = x + (size_t)row * CC;
  float v[4]; float ss = 0.f;
  #pragma unroll
  for (int i = 0; i < 4; i++){ v[i] = xr[threadIdx.x + 256*i]; ss += v[i]*v[i]; }
  #pragma unroll
  for (int off = 1; off < 64; off <<= 1) ss += __shfl_xor(ss, off);
  __shared__ float red[4];
  if ((threadIdx.x & 63) == 0) red[threadIdx.x >> 6] = ss;
  __syncthreads();
  float tot = red[0]+red[1]+red[2]+red[3];
  float rs = rsqrtf(tot * (1.f/CC) + 1e-6f);
  size_t base = (size_t)row * CC;
  #pragma unroll
  for (int i = 0; i < 4; i++){
    float r = v[i]*rs;
    unsigned short h = f2bf(r);
    oh[base + threadIdx.x + 256*i] = h;
    ol[base + threadIdx.x + 256*i] = f2bf(r - bf2f(h));
  }
}

// ---- all 7 weight splits in one launch; uniform per-block segment select ----
#define SQ4 262144
#define SK4 65536
#define SF4 1048576
__global__ __launch_bounds__(256) void splitall_k(
    const float* __restrict__ wq, const float* __restrict__ wk,
    const float* __restrict__ wv, const float* __restrict__ wo,
    const float* __restrict__ fi, const float* __restrict__ fo,
    const float* __restrict__ fg,
    unsigned short* __restrict__ hq, unsigned short* __restrict__ hk,
    unsigned short* __restrict__ hv, unsigned short* __restrict__ ho,
    unsigned short* __restrict__ hi, unsigned short* __restrict__ hfo,
    unsigned short* __restrict__ hg)
{
  int g = blockIdx.x*256 + threadIdx.x;   // float4 index
  const float* src; unsigned short* dh; int lo4; int n4;
  if (g < SQ4)                        { src=wq; dh=hq;  lo4=g;                     n4=SQ4; }
  else if (g < SQ4+SK4)               { src=wk; dh=hk;  lo4=g-SQ4;                 n4=SK4; }
  else if (g < SQ4+2*SK4)             { src=wv; dh=hv;  lo4=g-SQ4-SK4;             n4=SK4; }
  else if (g < 2*SQ4+2*SK4)           { src=wo; dh=ho;  lo4=g-SQ4-2*SK4;           n4=SQ4; }
  else if (g < 2*SQ4+2*SK4+SF4)       { src=fi; dh=hi;  lo4=g-2*SQ4-2*SK4;         n4=SF4; }
  else if (g < 2*SQ4+2*SK4+2*SF4)     { src=fo; dh=hfo; lo4=g-2*SQ4-2*SK4-SF4;     n4=SF4; }
  else                                { src=fg; dh=hg;  lo4=g-2*SQ4-2*SK4-2*SF4;   n4=SQ4; }
  unsigned short* dl = dh + (size_t)n4*4;
  float4 v = ((const float4*)src)[lo4];
  unsigned short h0 = f2bf(v.x), h1 = f2bf(v.y), h2v = f2bf(v.z), h3 = f2bf(v.w);
  ushort4 hvv = { h0, h1, h2v, h3 };
  ushort4 lvv = { f2bf(v.x - bf2f(h0)), f2bf(v.y - bf2f(h1)),
                  f2bf(v.z - bf2f(h2v)), f2bf(v.w - bf2f(h3)) };
  ((ushort4*)dh)[lo4] = hvv;
  ((ushort4*)dl)[lo4] = lvv;
}

// ---- bf16x3 MFMA GEMM, optional split-K via blockIdx.z (verified round 6) ----
template<int EPI>
__global__ __launch_bounds__(256) void gemm3_k(
    const unsigned short* __restrict__ Ah, const unsigned short* __restrict__ Al,
    const unsigned short* __restrict__ Wh, const unsigned short* __restrict__ Wl,
    float* __restrict__ C, int M, int N, int K, int KC)
{
  __shared__ unsigned short AhS[128*32];
  __shared__ unsigned short AlS[128*32];
  __shared__ unsigned short WhS[128*32];
  __shared__ unsigned short WlS[128*32];
  int tid  = threadIdx.x;
  int lane = tid & 63, wave = tid >> 6;
  int wr = wave >> 1, wc = wave & 1;
  int m0 = blockIdx.y << 7, n0 = blockIdx.x << 7;
  int z  = blockIdx.z;
  int kbase = z * KC;
  float* Cz = C + (size_t)z * M * N;
  int lr = lane & 15, lc = lane >> 4;

  int offA[4], offB[4];
  #pragma unroll
  for (int m = 0; m < 4; m++){
    int row = wr*64 + m*16 + lr;
    offA[m] = row*64 + ((lc ^ ((row >> 1) & 3)) << 4);
  }
  #pragma unroll
  for (int n = 0; n < 4; n++){
    int row = wc*64 + n*16 + lr;
    offB[n] = row*64 + ((lc ^ ((row >> 1) & 3)) << 4);
  }

  f32x4 acc[4][4] = {};

  for (int k0 = kbase; k0 < kbase + KC; k0 += 32){
    __syncthreads();
    {
      const unsigned short* srcs[4] = { Ah, Al, Wh, Wl };
      unsigned short* dsts[4] = { AhS, AlS, WhS, WlS };
      int rb[4] = { m0, m0, n0, n0 };
      #pragma unroll
      for (int tle = 0; tle < 4; tle++){
        #pragma unroll
        for (int i = 0; i < 2; i++){
          int s = i*256 + tid;
          int row = s >> 2;
          int c = (s & 3) ^ ((row >> 1) & 3);
          const unsigned short* gp = srcs[tle] + (size_t)(rb[tle] + row)*K + (k0 + c*8);
          unsigned short* lp = dsts[tle] + i*2048 + wave*512;
          __builtin_amdgcn_global_load_lds((const AS1 void*)gp, (AS3 void*)lp, 16, 0, 0);
        }
      }
    }
    __syncthreads();

    bf16x8 ah[4], al[4], bh[4], bl[4];
    #pragma unroll
    for (int m = 0; m < 4; m++){
      ah[m] = *(const bf16x8*)((const char*)AhS + offA[m]);
      al[m] = *(const bf16x8*)((const char*)AlS + offA[m]);
    }
    #pragma unroll
    for (int n = 0; n < 4; n++){
      bh[n] = *(const bf16x8*)((const char*)WhS + offB[n]);
      bl[n] = *(const bf16x8*)((const char*)WlS + offB[n]);
    }
    #pragma unroll
    for (int m = 0; m < 4; m++){
      #pragma unroll
      for (int n = 0; n < 4; n++){
        acc[m][n] = __builtin_amdgcn_mfma_f32_16x16x32_bf16(al[m], bh[n], acc[m][n], 0, 0, 0);
        acc[m][n] = __builtin_amdgcn_mfma_f32_16x16x32_bf16(ah[m], bl[n], acc[m][n], 0, 0, 0);
        acc[m][n] = __builtin_amdgcn_mfma_f32_16x16x32_bf16(ah[m], bh[n], acc[m][n], 0, 0, 0);
      }
    }
  }

  #pragma unroll
  for (int m = 0; m < 4; m++){
    int r0 = m0 + wr*64 + m*16 + lc*4;
    #pragma unroll
    for (int n = 0; n < 4; n++){
      int col = n0 + wc*64 + n*16 + lr;
      #pragma unroll
      for (int r = 0; r < 4; r++){
        float z2 = acc[m][n][r];
        if (EPI == 1){ z2 = fmaxf(z2, 0.f); z2 = z2*z2; }
        Cz[(size_t)(r0 + r)*N + col] = z2;
      }
    }
  }
}

// ---- sum split-K partials: out[i] = sum_z parts[z*n + i] ----
__global__ __launch_bounds__(256) void redsum_k(const float* __restrict__ p,
    float* __restrict__ o, size_t n, int parts){
  size_t i = ((size_t)blockIdx.x*256 + threadIdx.x)*4;
  float4 s = *(const float4*)(p + i);
  for (int z = 1; z < parts; z++){
    float4 q = *(const float4*)(p + (size_t)z*n + i);
    s.x += q.x; s.y += q.y; s.z += q.z; s.w += q.w;
  }
  *(float4*)(o + i) = s;
}

// ---- rope + head-rmsnorm * 1.2, fused split-K partial sum ----
__global__ __launch_bounds__(64) void rope_rms_sum_k(float* __restrict__ out,
    const float* __restrict__ parts, const float* __restrict__ cs,
    const float* __restrict__ sn, int nh, int nparts, size_t ps){
  int idx = blockIdx.x;                 // (b*T + t)*nh + h
  int t = (idx / nh) & (TT-1);
  int d = threadIdx.x;
  int dsw = (d < 32) ? d + 32 : d - 32;
  size_t base = (size_t)idx * HD;
  float v0 = 0.f, vp = 0.f;
  for (int z = 0; z < nparts; z++){
    v0 += parts[(size_t)z*ps + base + d];
    vp += parts[(size_t)z*ps + base + dsw];
  }
  int dl = d & 31;
  float c = cs[t*32 + dl], s = sn[t*32 + dl];
  float r = (d < 32) ? (v0*c + vp*s) : (v0*c - vp*s);
  float ss = r*r;
  #pragma unroll
  for (int off = 1; off < 64; off <<= 1) ss += __shfl_xor(ss, off);
  float rs = rsqrtf(ss*(1.f/HD) + 1e-6f) * 1.2f;
  out[base + d] = r*rs;
}

// ---- v = sum_z vpart + 3*sigmoid(xn[:,:12] @ wg^T) * ve ----
__global__ __launch_bounds__(256) void gatev_k(float* __restrict__ v,
    const float* __restrict__ vparts, int nparts, size_t ps,
    const unsigned short* __restrict__ xnh, const unsigned short* __restrict__ xnl,
    const float* __restrict__ ve, const float* __restrict__ wg){
  int bt = blockIdx.x;
  int tid = threadIdx.x;
  int kv = tid >> 6;
  float s = 0.f;
  #pragma unroll
  for (int j = 0; j < 12; j++){
    float xv = bf2f(xnh[(size_t)bt*CC + j]) + bf2f(xnl[(size_t)bt*CC + j]);
    s += xv*wg[kv*12+j];
  }
  float gate = 3.f * sigf(s);
  size_t i = (size_t)bt*(NKV*HD) + tid;
  float sv = 0.f;
  for (int z = 0; z < nparts; z++) sv += vparts[(size_t)z*ps + i];
  v[i] = sv + gate * ve[i];
}

// ---- MFMA flash attention (S^T trick), round 7: K hi-only plane dropped (bf16x2 QK),
//      LDS 34 KB -> 4 blocks/CU. Q stays hi/lo compensated. ----
__global__ __launch_bounds__(256) void fattn_k(
    const float* __restrict__ q, const float* __restrict__ k, const float* __restrict__ v,
    const float* __restrict__ pa, const float* __restrict__ rw,
    const float* __restrict__ alphap,
    unsigned short* __restrict__ yh, unsigned short* __restrict__ yl)
{
  int qt = blockIdx.x;
  int h  = blockIdx.y;
  int b  = blockIdx.z;
  int kv = h >> 2;
  int t0 = qt * TQ;
  int tid = threadIdx.x;
  int lane = tid & 63, w = tid >> 6;
  int dl = lane & 15, gq = lane >> 4;

  __shared__ __align__(16) unsigned short Kh[4096];             // [64 k][64 d] swz, bf16 hi
  __shared__ __align__(16) unsigned short Vh[64][68];           // [k][d] bf16 hi
  __shared__ __align__(16) unsigned short SBs[66*68];           // pa tile bf16
  __shared__ __align__(16) unsigned short Ph[4][1024];          // per-wave P [16 q][64 k] swz, hi

  // Q fragments direct from global (lane's q row = 16w+dl)
  bf16x8 qfh[2], qfl[2];
  {
    const float* qrow = q + (((size_t)(b*TT + t0 + 16*w + dl))*NH + h)*HD;
    #pragma unroll
    for (int ks = 0; ks < 2; ks++){
      float4 a = *(const float4*)(qrow + (gq+4*ks)*8);
      float4 bq = *(const float4*)(qrow + (gq+4*ks)*8 + 4);
      float vv[8] = {a.x,a.y,a.z,a.w,bq.x,bq.y,bq.z,bq.w};
      #pragma unroll
      for (int i = 0; i < 8; i++){
        unsigned short hv = f2bf(vv[i]);
        qfh[ks][i] = (short)hv;
        qfl[ks][i] = (short)f2bf(vv[i] - bf2f(hv));
      }
    }
  }

  float alpha = *alphap;
  float w9[9];
  #pragma unroll
  for (int j = 0; j < 9; j++) w9[j] = rw[h*9+j]*alpha;

  float m_i = -1e30f, l_i = 0.f;
  f32x4 acc_o[4] = {};
  int ql = 16*w + dl;

  for (int kt = 0; kt <= qt; kt++){
    int k0 = kt*TK;
    __syncthreads();
    #pragma unroll
    for (int it = 0; it < 4; it++){
      int s = it*256 + tid;
      int r = s >> 4, d4 = (s & 15) << 2;
      const float* kp = k + (((size_t)(b*TT + k0 + r))*NKV + kv)*HD + d4;
      float4 val = *(const float4*)kp;
      ushort4 hv = { f2bf(val.x), f2bf(val.y), f2bf(val.z), f2bf(val.w) };
      int idx = r*64 + (((d4 >> 3) ^ (r & 7)) << 3) + (d4 & 7);
      *(ushort4*)&Kh[idx] = hv;
      const float* vp = v + (((size_t)(b*TT + k0 + r))*NKV + kv)*HD + d4;
      float4 vval = *(const float4*)vp;
      ushort4 vh4 = { f2bf(vval.x), f2bf(vval.y), f2bf(vval.z), f2bf(vval.w) };
      *(ushort4*)&Vh[r][d4] = vh4;
    }
    #pragma unroll
    for (int it = 0; it < 4; it++){
      int e = it*256 + tid;
      int r = e >> 4, c4 = (e & 15) << 2;
      const float* pp = pa + ((size_t)(b*NH + h)*TT + (t0 + r))*TT + (k0 + c4);
      float4 pv = *(const float4*)pp;
      unsigned short* sp = &SBs[(r+1)*68 + (c4+1)];
      sp[0] = f2bf(pv.x); sp[1] = f2bf(pv.y); sp[2] = f2bf(pv.z); sp[3] = f2bf(pv.w);
    }
    for (int e = tid; e < 260; e += 256){
      int li, lj;
      if (e < 132){ li = (e < 66) ? 0 : 65; lj = (e < 66) ? e : e - 66; }
      else { int idx = e - 132; li = 1 + (idx & 63); lj = (idx >> 6) ? 65 : 0; }
      int gr = t0 - 1 + li, gc = k0 - 1 + lj;
      float pv = 0.f;
      if (gr >= 0 && gr < TT && gc >= 0 && gc < TT)
        pv = pa[((size_t)(b*NH + h)*TT + gr)*TT + gc];
      SBs[li*68 + lj] = f2bf(pv);
    }
    __syncthreads();

    // S^T = K·Q^T (bf16x2: Kh·Qh + Kh·Ql; K-lo term dropped, ~0.2% logit err)
    f32x4 acc_s[4] = {};
    __builtin_amdgcn_s_setprio(1);
    #pragma unroll
    for (int ks = 0; ks < 2; ks++){
      #pragma unroll
      for (int kf = 0; kf < 4; kf++){
        int row = 16*kf + dl;
        int idx = row*64 + (((gq + 4*ks) ^ (row & 7)) << 3);
        bf16x8 kh_ = *(const bf16x8*)&Kh[idx];
        acc_s[kf] = __builtin_amdgcn_mfma_f32_16x16x32_bf16(kh_, qfl[ks], acc_s[kf], 0, 0, 0);
        acc_s[kf] = __builtin_amdgcn_mfma_f32_16x16x32_bf16(kh_, qfh[ks], acc_s[kf], 0, 0, 0);
      }
    }
    __builtin_amdgcn_s_setprio(0);

    #pragma unroll
    for (int kf = 0; kf < 4; kf++){
      int kb = 16*kf + 4*gq;
      float cv0=0.f, cv1=0.f, cv2=0.f, cv3=0.f;
      #pragma unroll
      for (int dy = 0; dy < 3; dy++){
        const unsigned short* rp = &SBs[(ql + dy)*68 + kb];
        float u0 = bf2f(rp[0]), u1 = bf2f(rp[1]), u2 = bf2f(rp[2]),
              u3 = bf2f(rp[3]), u4 = bf2f(rp[4]), u5 = bf2f(rp[5]);
        float wa = w9[dy*3+0], wb = w9[dy*3+1], wcq = w9[dy*3+2];
        cv0 += u0*wa + u1*wb + u2*wcq;
        cv1 += u1*wa + u2*wb + u3*wcq;
        cv2 += u2*wa + u3*wb + u4*wcq;
        cv3 += u3*wa + u4*wb + u5*wcq;
      }
      int grow = t0 + ql;
      float s0 = acc_s[kf][0]*0.125f + cv0; if (k0 + kb + 0 > grow) s0 = -1e30f;
      float s1 = acc_s[kf][1]*0.125f + cv1; if (k0 + kb + 1 > grow) s1 = -1e30f;
      float s2 = acc_s[kf][2]*0.125f + cv2; if (k0 + kb + 2 > grow) s2 = -1e30f;
      float s3 = acc_s[kf][3]*0.125f + cv3; if (k0 + kb + 3 > grow) s3 = -1e30f;
      acc_s[kf][0] = s0; acc_s[kf][1] = s1; acc_s[kf][2] = s2; acc_s[kf][3] = s3;
    }

    float rm = -1e30f;
    #pragma unroll
    for (int kf = 0; kf < 4; kf++){
      rm = fmaxf(rm, fmaxf(fmaxf(acc_s[kf][0], acc_s[kf][1]),
                           fmaxf(acc_s[kf][2], acc_s[kf][3])));
    }
    rm = fmaxf(rm, __shfl_xor(rm, 16));
    rm = fmaxf(rm, __shfl_xor(rm, 32));
    float mn = fmaxf(m_i, rm);
    float sc = __expf(m_i - mn);
    m_i = mn;
    float rs = 0.f;
    #pragma unroll
    for (int kf = 0; kf < 4; kf++){
      float p0 = __expf(acc_s[kf][0] - mn);
      float p1 = __expf(acc_s[kf][1] - mn);
      float p2 = __expf(acc_s[kf][2] - mn);
      float p3 = __expf(acc_s[kf][3] - mn);
      rs += p0 + p1 + p2 + p3;
      ushort4 hv = { f2bf(p0), f2bf(p1), f2bf(p2), f2bf(p3) };
      int kbl = 16*kf + 4*gq;
      int idx = dl*64 + ((((kbl >> 3)) ^ (dl & 7)) << 3) + (kbl & 7);
      *(ushort4*)&Ph[w][idx] = hv;
    }
    rs += __shfl_xor(rs, 16);
    rs += __shfl_xor(rs, 32);
    l_i = l_i*sc + rs;

    float scR0 = __shfl(sc, gq*4 + 0);
    float scR1 = __shfl(sc, gq*4 + 1);
    float scR2 = __shfl(sc, gq*4 + 2);
    float scR3 = __shfl(sc, gq*4 + 3);
    #pragma unroll
    for (int nf = 0; nf < 4; nf++){
      acc_o[nf][0] *= scR0; acc_o[nf][1] *= scR1;
      acc_o[nf][2] *= scR2; acc_o[nf][3] *= scR3;
    }

    #pragma unroll
    for (int ks = 0; ks < 2; ks++){
      int idxp = dl*64 + (((gq + 4*ks) ^ (dl & 7)) << 3);
      bf16x8 pfh = *(const bf16x8*)&Ph[w][idxp];
      __builtin_amdgcn_s_setprio(1);
      #pragma unroll
      for (int nf = 0; nf < 4; nf++){
        bf16x8 vh_;
        #pragma unroll
        for (int i = 0; i < 8; i++)
          vh_[i] = (short)Vh[ks*32 + gq*8 + i][16*nf + dl];
        acc_o[nf] = __builtin_amdgcn_mfma_f32_16x16x32_bf16(pfh, vh_, acc_o[nf], 0, 0, 0);
      }
      __builtin_amdgcn_s_setprio(0);
    }
  }

  float li0 = __shfl(l_i, gq*4 + 0);
  float li1 = __shfl(l_i, gq*4 + 1);
  float li2 = __shfl(l_i, gq*4 + 2);
  float li3 = __shfl(l_i, gq*4 + 3);
  float inv0 = 1.f/li0, inv1 = 1.f/li1, inv2 = 1.f/li2, inv3 = 1.f/li3;
  #pragma unroll
  for (int nf = 0; nf < 4; nf++){
    int dcol = 16*nf + dl;
    #pragma unroll
    for (int reg = 0; reg < 4; reg++){
      float invv = (reg == 0) ? inv0 : (reg == 1) ? inv1 : (reg == 2) ? inv2 : inv3;
      float val = acc_o[nf][reg] * invv;
      size_t bix = (((size_t)(b*TT + t0 + 16*w + gq*4 + reg))*NH + h)*HD + dcol;
      unsigned short hv = f2bf(val);
      yh[bix] = hv;
      yl[bix] = f2bf(val - bf2f(hv));
    }
  }
}

// ---- CA: in-projection (K=1024 -> 32) ----
__global__ __launch_bounds__(256) void cain_k(const float* __restrict__ x,
    const float* __restrict__ pi, float* __restrict__ out){
  int bt = blockIdx.x;
  __shared__ float xs[CC];
  __shared__ float pr[8][33];
  for (int i = threadIdx.x; i < CC; i += 256) xs[i] = x[(size_t)bt*CC + i];
  __syncthreads();
  int d = threadIdx.x & 31, sl = threadIdx.x >> 5;
  const float* pip = pi + (size_t)d*CC + sl*128;
  float s = 0.f;
  #pragma unroll 8
  for (int i = 0; i < 128; i++) s += xs[sl*128+i]*pip[i];
  pr[sl][d] = s;
  __syncthreads();
  if (threadIdx.x < 32){
    float tot = 0.f;
    #pragma unroll
    for (int j = 0; j < 8; j++) tot += pr[j][threadIdx.x];
    out[(size_t)bt*CAD + threadIdx.x] = tot;
  }
}

// ---- CA: depthwise conv over T + exact gelu ----
__global__ __launch_bounds__(256) void caconv_k(const float* __restrict__ hin,
    const float* __restrict__ cw, float* __restrict__ gout){
  int i = blockIdx.x*256 + threadIdx.x;
  int d = i & 31;
  int bt = i >> 5;
  int t = bt & (TT-1);
  float cc = hin[i];
  float hm = (t > 0)      ? hin[i-32] : 0.f;
  float hp = (t < TT-1)   ? hin[i+32] : 0.f;
  float hc = cc + 0.1f*(hm*cw[d*3] + cc*cw[d*3+1] + hp*cw[d*3+2]);
  gout[i] = geluf(hc);
}

// ---- CA: out-projection (K=32 -> 1024) ----
__global__ __launch_bounds__(256) void caout_k(const float* __restrict__ g,
    const float* __restrict__ po, float* __restrict__ out){
  int bt = blockIdx.x;
  __shared__ float gs[CAD];
  if (threadIdx.x < CAD) gs[threadIdx.x] = g[(size_t)bt*CAD + threadIdx.x];
  __syncthreads();
  for (int c = threadIdx.x; c < CC; c += 256){
    const float* pp = po + (size_t)c*CAD;
    float s = 0.f;
    #pragma unroll
    for (int d2 = 0; d2 < CAD; d2++) s += gs[d2]*pp[d2];
    out[(size_t)bt*CC + c] = s;
  }
}

// ---- x1 = x + (sum of o partials) * (1 + 0.1*tanh(ca1)) ----
__global__ __launch_bounds__(256) void x1_k(const float* __restrict__ x,
    const float* __restrict__ opart, size_t ps,
    const float* __restrict__ ca1, float* __restrict__ x1){
  size_t i = (size_t)blockIdx.x*256 + threadIdx.x;
  float ao = opart[i] + opart[i + ps];
  x1[i] = x[i] + ao * (1.f + 0.1f*tanhf(ca1[i]));
}

// ---- fused 4-pass FFN depthwise conv (register cascade), bf16 pair out ----
__global__ __launch_bounds__(256) void ffnconv4_k(const float* __restrict__ hin,
    const float* __restrict__ cw, unsigned short* __restrict__ hh, unsigned short* __restrict__ hl){
  int c  = blockIdx.x*256 + threadIdx.x;
  int ta = blockIdx.y*64;
  int b  = blockIdx.z;
  float w0 = cw[c*3+0], w1 = cw[c*3+1], w2 = cw[c*3+2];
  size_t base = (size_t)b*TT*FFNH + c;
  float i0=0.f,i1=0.f,i2=0.f;
  float a0=0.f,a1=0.f,a2=0.f;
  float b0=0.f,b1=0.f,b2=0.f;
  float c0=0.f,c1=0.f,c2=0.f;
  for (int t = ta-4; t <= ta+67; t++){
    float iv = 0.f;
    if (t >= 0 && t < TT) iv = hin[base + (size_t)t*FFNH];
    i0 = i1; i1 = i2; i2 = iv;
    float s1 = i1 + 0.1f*(i0*w0 + i1*w1 + i2*w2);
    if (t-1 < 0 || t-1 >= TT) s1 = 0.f;
    a0 = a1; a1 = a2; a2 = s1;
    float s2 = a1 + 0.1f*(a0*w0 + a1*w1 + a2*w2);
    if (t-2 < 0 || t-2 >= TT) s2 = 0.f;
    b0 = b1; b1 = b2; b2 = s2;
    float s3 = b1 + 0.1f*(b0*w0 + b1*w1 + b2*w2);
    if (t-3 < 0 || t-3 >= TT) s3 = 0.f;
    c0 = c1; c1 = c2; c2 = s3;
    float s4 = c1 + 0.1f*(c0*w0 + c1*w1 + c2*w2);
    int t4 = t-4;
    if (t4 >= ta){
      size_t oix = base + (size_t)t4*FFNH;
      unsigned short hv = f2bf(s4);
      hh[oix] = hv;
      hl[oix] = f2bf(s4 - bf2f(hv));
    }
  }
}

// ---- vit scalar gate ----
__global__ __launch_bounds__(256) void vit_k(const float* __restrict__ x1,
    const float* __restrict__ w1, const float* __restrict__ w2,
    float* __restrict__ vout){
  int bt = blockIdx.x;
  __shared__ float xs[CC];
  __shared__ float pr[8][33];
  __shared__ float g32[32];
  for (int i = threadIdx.x; i < CC; i += 256) xs[i] = x1[(size_t)bt*CC + i];
  __syncthreads();
  int d = threadIdx.x & 31, sl = threadIdx.x >> 5;
  const float* wp = w1 + (size_t)d*CC + sl*128;
  float s = 0.f;
  #pragma unroll 8
  for (int i = 0; i < 128; i++) s += xs[sl*128+i]*wp[i];
  pr[sl][d] = s;
  __syncthreads();
  if (threadIdx.x < 32){
    float tot = 0.f;
    #pragma unroll
    for (int j = 0; j < 8; j++) tot += pr[j][threadIdx.x];
    g32[threadIdx.x] = geluf(tot);
  }
  __syncthreads();
  if (threadIdx.x == 0){
    float s2 = 0.f;
    #pragma unroll
    for (int d2 = 0; d2 < 32; d2++) s2 += g32[d2]*w2[d2];
    vout[bt] = sigf(s2);
  }
}

// ---- vit smoothing + threshold ----
__global__ __launch_bounds__(256) void vitsm_k(const float* __restrict__ vin, float* __restrict__ vout){
  int i = blockIdx.x*256 + threadIdx.x;
  int t = i & (TT-1), b = i >> 10;
  float s = 0.f;
  #pragma unroll
  for (int dd = -2; dd <= 2; dd++){
    int tt = t + dd;
    if (tt >= 0 && tt < TT) s += vin[(b << 10) + tt];
  }
  s *= 0.2f;
  float vv = 0.7f*vin[i] + 0.3f*s;
  vout[i] = (vv > 0.3f) ? vv : 0.1f*vv;
}

// ---- final: out = x1 + mlp*sig(g)*(1+0.1*tanh(ca2)) * vit ----
__global__ __launch_bounds__(256) void final_k(const float* __restrict__ x1,
    const float* __restrict__ mlpraw, const float* __restrict__ g,
    const float* __restrict__ ca2, const float* __restrict__ vsm,
    float* __restrict__ out){
  size_t i = (size_t)blockIdx.x*256 + threadIdx.x;
  size_t bt = i >> 10;
  float mlp = mlpraw[i] * sigf(g[i]) * (1.f + 0.1f*tanhf(ca2[i]));
  out[i] = x1[i] + mlp * vsm[bt];
}

extern "C" void kernel_launch(void* const* d_in, const int* in_sizes, int n_in,
                              void* d_out, int out_size, void* d_ws, size_t ws_size,
                              hipStream_t stream) {
  (void)in_sizes; (void)n_in; (void)out_size; (void)ws_size;
  const float* x     = (const float*)d_in[0];
  const float* ve    = (const float*)d_in[1];
  const float* cs    = (const float*)d_in[2];
  const float* sn    = (const float*)d_in[3];
  const float* pa    = (const float*)d_in[4];
  const float* w_q   = (const float*)d_in[5];
  const float* w_k   = (const float*)d_in[6];
  const float* w_v   = (const float*)d_in[7];
  const float* w_o   = (const float*)d_in[8];
  const float* w_vg  = (const float*)d_in[9];
  const float* rfw   = (const float*)d_in[10];
  const float* ralp  = (const float*)d_in[11];
  const float* capi  = (const float*)d_in[12];
  const float* cacw  = (const float*)d_in[13];
  const float* capo  = (const float*)d_in[14];
  const float* ffin  = (const float*)d_in[15];
  const float* ffcw  = (const float*)d_in[16];
  const float* ffout = (const float*)d_in[17];
  const float* ffgt  = (const float*)d_in[18];
  const float* vw1   = (const float*)d_in[19];
  const float* vw2   = (const float*)d_in[20];

  // ---- workspace layout (lifetimes disjoint where aliased), 232 MiB total ----
  const size_t M4  = (size_t)BB*TT*CC;      // 4,194,304 elements
  const size_t MB1 = 1ull << 20;
  char* WSB = (char*)d_ws;

  unsigned short* xnh = (unsigned short*)WSB;          //  0..16MiB: xn/xm bf16 pair
  unsigned short* xnl = xnh + M4;
  float* ca1 = (float*)WSB;                            //  (alias, after xn consumed)
  float* qb  = (float*)(WSB + 16*MB1);                 // 16..32: q fp32 (later: ffn gate)
  float* kb  = (float*)(WSB + 32*MB1);                 // 32..36: k fp32
  float* vb  = (float*)(WSB + 36*MB1);                 // 36..40: v fp32 (later: ca scratch)
  float* cah = (float*)(WSB + 36*MB1);
  float* cag = cah + (size_t)BB*TT*CAD;
  float* vtb = cag + (size_t)BB*TT*CAD;
  float* vsm = vtb + (size_t)BB*TT;
  unsigned short* ffgp = (unsigned short*)(WSB + 40*MB1); // 40..48: ffgt pair (ao region head)
  float* ao  = (float*)(WSB + 40*MB1);                 // 40..56: mlp raw (written after ffgp dead)
  float* x1b = (float*)(WSB + 56*MB1);                 // 56..72: x1 fp32 (early: y pair)
  unsigned short* yh = (unsigned short*)x1b;
  unsigned short* yl = yh + M4;
  float* hb  = (float*)(WSB + 72*MB1);                 // 72..136: partial pool / h fp32
  float* h2  = (float*)(WSB + 136*MB1);                // 136..200: h bf16 pair (early: qkvo pairs, late: ca2)
  unsigned short* hh = (unsigned short*)h2;
  unsigned short* hl = hh + 4*M4;
  unsigned short* wqp = (unsigned short*)(WSB + 136*MB1);
  unsigned short* wkp = (unsigned short*)(WSB + 140*MB1);
  unsigned short* wvp = (unsigned short*)(WSB + 141*MB1);
  unsigned short* wop = (unsigned short*)(WSB + 142*MB1);
  float* ca2 = h2;
  unsigned short* ffip = (unsigned short*)(WSB + 200*MB1); // 200..216: ffn_in pair
  unsigned short* ffop = (unsigned short*)(WSB + 216*MB1); // 216..232: ffn_out pair

  // split-K partial pool (inside hb; phases disjoint by stream order)
  float* kpart = hb;                                   // 4 x 4MB   (early)
  float* vpart = hb + 4*M4/4;                          // 4 x 4MB   (early)
  float* qpart = hb + 8*M4/4;                          // 2 x 16MB  (early)
  float* opart = hb;                                   // 2 x 16MB  (after fattn; read by x1_k)
  float* gpart = hb;                                   // 2 x 16MB  (after ffnconv4)
  float* fpart = hb;                                   // 4 x 16MB  (after gate redsum)

  const int BT = BB*TT;                     // 4096
  const int WQN = NH*HD*CC;                 // 1,048,576

  // all weight splits in one launch (3014656 float4s)
  splitall_k<<<11776, 256, 0, stream>>>(w_q, w_k, w_v, w_o, ffin, ffout, ffgt,
                                        wqp, wkp, wvp, wop, ffip, ffop, ffgp);

  rmsnorm_pair_k<<<BT, 256, 0, stream>>>(x, xnh, xnl);
  gemm3_k<0><<<dim3(8, 32, 2), 256, 0, stream>>>(xnh, xnl, wqp, wqp + WQN, qpart, BT, 1024, 1024, 512);
  gemm3_k<0><<<dim3(2, 32, 4), 256, 0, stream>>>(xnh, xnl, wkp, wkp + NKV*HD*CC, kpart, BT, 256, 1024, 256);
  gemm3_k<0><<<dim3(2, 32, 4), 256, 0, stream>>>(xnh, xnl, wvp, wvp + NKV*HD*CC, vpart, BT, 256, 1024, 256);
  rope_rms_sum_k<<<BT*NH, 64, 0, stream>>>(qb, qpart, cs, sn, NH, 2, (size_t)BT*1024);
  rope_rms_sum_k<<<BT*NKV, 64, 0, stream>>>(kb, kpart, cs, sn, NKV, 4, (size_t)BT*256);
  gatev_k<<<BT, 256, 0, stream>>>(vb, vpart, 4, (size_t)BT*256, xnh, xnl, ve, w_vg);
  fattn_k<<<dim3(TT/TQ, NH, BB), 256, 0, stream>>>(qb, kb, vb, pa, rfw, ralp, yh, yl);
  // o-projection: partials into hb (consumed by fused x1_k)
  gemm3_k<0><<<dim3(8, 32, 2), 256, 0, stream>>>(yh, yl, wop, wop + WQN, opart, BT, 1024, 1024, 512);
  cain_k<<<BT, 256, 0, stream>>>(x, capi, cah);
  caconv_k<<<BT*CAD/256, 256, 0, stream>>>(cah, cacw, cag);
  caout_k<<<BT, 256, 0, stream>>>(cag, capo, ca1);
  x1_k<<<BT*CC/256, 256, 0, stream>>>(x, opart, (size_t)BT*1024, ca1, x1b);
  rmsnorm_pair_k<<<BT, 256, 0, stream>>>(x1b, xnh, xnl);      // xm pair
  gemm3_k<1><<<dim3(32, 32), 256, 0, stream>>>(xnh, xnl, ffip, ffip + M4, hb, BT, FFNH, 1024, 1024);
  ffnconv4_k<<<dim3(FFNH/256, TT/64, BB), 256, 0, stream>>>(hb, ffcw, hh, hl);
  // gate: partials in hb (free after ffnconv4), reduce into qb
  gemm3_k<0><<<dim3(8, 32, 2), 256, 0, stream>>>(xnh, xnl, ffgp, ffgp + WQN, gpart, BT, 1024, 1024, 512);
  redsum_k<<<4096, 256, 0, stream>>>(gpart, qb, (size_t)BT*1024, 2);
  // ffn_out: split-K=4 partials in hb, reduce into ao (ffgp dead after gate GEMM)
  gemm3_k<0><<<dim3(8, 32, 4), 256, 0, stream>>>(hh, hl, ffop, ffop + M4, fpart, BT, 1024, 4096, 1024);
  redsum_k<<<4096, 256, 0, stream>>>(fpart, ao, (size_t)BT*1024, 4);
  cain_k<<<BT, 256, 0, stream>>>(x1b, capi, cah);
  caconv_k<<<BT*CAD/256, 256, 0, stream>>>(cah, cacw, cag);
  caout_k<<<BT, 256, 0, stream>>>(cag, capo, ca2);
  vit_k<<<BT, 256, 0, stream>>>(x1b, vw1, vw2, vtb);
  vitsm_k<<<BT/256, 256, 0, stream>>>(vtb, vsm);
  final_k<<<BT*CC/256, 256, 0, stream>>>(x1b, ao, qb, ca2, vsm, (float*)d_out);
}